// Round 1
// baseline (2115.189 us; speedup 1.0000x reference)
//
#include <hip/hip_runtime.h>
#include <hip/hip_bf16.h>
#include <math.h>

#define Bb 2
#define Tt 2048
#define Dd 1024
#define Hh 16
#define HD 64

// ---------------------------------------------------------------------------
// Tiled fp32 GEMM: C[M,N] = A[M,K] @ B[K,N] + bias[N]
// 64x64 tile, BK=16, 256 threads, 4x4 micro-tile per thread.
// ---------------------------------------------------------------------------
__global__ __launch_bounds__(256) void sgemm_bias(
    const float* __restrict__ A, const float* __restrict__ Bm,
    const float* __restrict__ bias, float* __restrict__ C,
    int M, int N, int K)
{
    __shared__ float As[16][65];   // As[k][m]  (+1 pad: conflict-free)
    __shared__ float Bs[16][68];   // Bs[k][n]  (+4 pad: keeps float4 align)

    const int tid  = threadIdx.x;
    const int tx   = tid & 15;     // 0..15 -> 4 output cols each
    const int ty   = tid >> 4;     // 0..15 -> 4 output rows each
    const int row0 = blockIdx.y * 64;
    const int col0 = blockIdx.x * 64;

    float acc[4][4];
    #pragma unroll
    for (int i = 0; i < 4; ++i)
        #pragma unroll
        for (int j = 0; j < 4; ++j) acc[i][j] = 0.f;

    const int arow = tid >> 2;     // 0..63
    const int kq   = tid & 3;      // 0..3  (16-float K slab / 4)
    const int krow = tid >> 4;     // 0..15
    const int nq   = tid & 15;     // 0..15

    for (int ko = 0; ko < K; ko += 16) {
        // stage A tile [64 rows][16 k] transposed into As[k][m]
        const float4 va = *(const float4*)&A[(size_t)(row0 + arow) * K + ko + kq * 4];
        As[kq * 4 + 0][arow] = va.x;
        As[kq * 4 + 1][arow] = va.y;
        As[kq * 4 + 2][arow] = va.z;
        As[kq * 4 + 3][arow] = va.w;
        // stage B tile [16 k][64 cols]
        const float4 vb = *(const float4*)&Bm[(size_t)(ko + krow) * N + col0 + nq * 4];
        *(float4*)&Bs[krow][nq * 4] = vb;
        __syncthreads();

        #pragma unroll
        for (int kk = 0; kk < 16; ++kk) {
            float a[4];
            #pragma unroll
            for (int i = 0; i < 4; ++i) a[i] = As[kk][ty * 4 + i];
            const float4 b4 = *(const float4*)&Bs[kk][tx * 4];
            #pragma unroll
            for (int i = 0; i < 4; ++i) {
                acc[i][0] += a[i] * b4.x;
                acc[i][1] += a[i] * b4.y;
                acc[i][2] += a[i] * b4.z;
                acc[i][3] += a[i] * b4.w;
            }
        }
        __syncthreads();
    }

    // epilogue: bias + store (float4)
    const float4 bi = *(const float4*)&bias[col0 + tx * 4];
    #pragma unroll
    for (int i = 0; i < 4; ++i) {
        float4 o;
        o.x = acc[i][0] + bi.x;
        o.y = acc[i][1] + bi.y;
        o.z = acc[i][2] + bi.z;
        o.w = acc[i][3] + bi.w;
        *(float4*)&C[(size_t)(row0 + ty * 4 + i) * N + col0 + tx * 4] = o;
    }
}

// ---------------------------------------------------------------------------
// Flash-style causal attention, fp32.
// qkv layout: [B*T][3072], cols 0..1023 = Q (head-major), 1024.. = K, 2048.. = V
// One block per (q-tile of 64 rows, head, batch). 256 threads:
//   thread t -> q-row r = t/4, quad slot cq = t%3? no: cq = t%4 -> 16-col slab.
// Online softmax state (m, l) per row, O accumulator 16 floats/thread.
// ---------------------------------------------------------------------------
__global__ __launch_bounds__(256) void attn_kernel(
    const float* __restrict__ qkv, float* __restrict__ attn_out)
{
    const int qt  = blockIdx.x;    // 0..31
    const int h   = blockIdx.y;    // 0..15
    const int b   = blockIdx.z;    // 0..1
    const int tid = threadIdx.x;
    const int r   = tid >> 2;      // q row within tile, 0..63
    const int cb  = (tid & 3) * 16;// col slab base (S cols / O dims)

    __shared__ float Qs[64][65];
    __shared__ float Ks[64][65];
    __shared__ float Vs[64][65];
    __shared__ float Ps[64][65];

    const int q0 = qt * 64;

    // load Q tile: Qs[rr][d]
    #pragma unroll
    for (int i = 0; i < 4; ++i) {
        const int rr = (tid >> 4) + i * 16;
        const int d4 = (tid & 15) * 4;
        const float4 v = *(const float4*)&qkv[(size_t)(b * Tt + q0 + rr) * 3072 + h * 64 + d4];
        Qs[rr][d4 + 0] = v.x; Qs[rr][d4 + 1] = v.y;
        Qs[rr][d4 + 2] = v.z; Qs[rr][d4 + 3] = v.w;
    }

    float o[16];
    #pragma unroll
    for (int i = 0; i < 16; ++i) o[i] = 0.f;
    float m_prev = -__builtin_huge_valf();
    float l_prev = 0.f;
    const float scale = 0.125f;    // 1/sqrt(64)

    for (int kt = 0; kt <= qt; ++kt) {
        const int k0 = kt * 64;
        __syncthreads();  // prev iter done with Ks/Vs/Ps (and Qs visible, iter 0)

        // stage K and V tiles
        #pragma unroll
        for (int i = 0; i < 4; ++i) {
            const int rr = (tid >> 4) + i * 16;
            const int d4 = (tid & 15) * 4;
            const size_t rowK = (size_t)(b * Tt + k0 + rr) * 3072;
            const float4 kv = *(const float4*)&qkv[rowK + 1024 + h * 64 + d4];
            Ks[rr][d4 + 0] = kv.x; Ks[rr][d4 + 1] = kv.y;
            Ks[rr][d4 + 2] = kv.z; Ks[rr][d4 + 3] = kv.w;
            const float4 vv = *(const float4*)&qkv[rowK + 2048 + h * 64 + d4];
            Vs[rr][d4 + 0] = vv.x; Vs[rr][d4 + 1] = vv.y;
            Vs[rr][d4 + 2] = vv.z; Vs[rr][d4 + 3] = vv.w;
        }
        __syncthreads();

        // S = Q K^T for this thread's 16 columns
        float s[16];
        #pragma unroll
        for (int c = 0; c < 16; ++c) s[c] = 0.f;
        for (int d0 = 0; d0 < 64; d0 += 8) {
            float qreg[8];
            #pragma unroll
            for (int j = 0; j < 8; ++j) qreg[j] = Qs[r][d0 + j];
            #pragma unroll
            for (int c = 0; c < 16; ++c) {
                #pragma unroll
                for (int j = 0; j < 8; ++j)
                    s[c] += qreg[j] * Ks[cb + c][d0 + j];
            }
        }

        // scale + causal mask + row max
        const int qi = q0 + r;
        float mloc = -__builtin_huge_valf();
        #pragma unroll
        for (int c = 0; c < 16; ++c) {
            const int ki = k0 + cb + c;
            s[c] = (ki <= qi) ? s[c] * scale : -__builtin_huge_valf();
            mloc = fmaxf(mloc, s[c]);
        }
        mloc = fmaxf(mloc, __shfl_xor(mloc, 1));
        mloc = fmaxf(mloc, __shfl_xor(mloc, 2));
        const float m_new = fmaxf(m_prev, mloc);
        const float alpha = __expf(m_prev - m_new);  // exp(-inf)=0 on first tile

        float lsum = 0.f;
        #pragma unroll
        for (int c = 0; c < 16; ++c) {
            const float p = __expf(s[c] - m_new);    // masked -> exp(-inf)=0
            Ps[r][cb + c] = p;
            lsum += p;
        }
        lsum += __shfl_xor(lsum, 1);
        lsum += __shfl_xor(lsum, 2);
        l_prev = l_prev * alpha + lsum;
        m_prev = m_new;
        #pragma unroll
        for (int i = 0; i < 16; ++i) o[i] *= alpha;

        __syncthreads();  // all Ps written

        // O += P V for this thread's 16 dims
        for (int c0 = 0; c0 < 64; c0 += 8) {
            float p8[8];
            #pragma unroll
            for (int j = 0; j < 8; ++j) p8[j] = Ps[r][c0 + j];
            #pragma unroll
            for (int j = 0; j < 8; ++j) {
                #pragma unroll
                for (int i = 0; i < 16; ++i)
                    o[i] += p8[j] * Vs[c0 + j][cb + i];
            }
        }
    }

    const float inv_l = 1.0f / l_prev;
    const size_t orow = (size_t)(b * Tt + q0 + r) * 1024 + h * 64 + cb;
    #pragma unroll
    for (int i = 0; i < 16; ++i)
        attn_out[orow + i] = o[i] * inv_l;
}

// ---------------------------------------------------------------------------
extern "C" void kernel_launch(void* const* d_in, const int* in_sizes, int n_in,
                              void* d_out, int out_size, void* d_ws, size_t ws_size,
                              hipStream_t stream) {
    const float* x    = (const float*)d_in[0];   // [B,T,D]
    const float* Wqkv = (const float*)d_in[1];   // [D,3D]
    const float* bqkv = (const float*)d_in[2];   // [3D]
    const float* Wout = (const float*)d_in[3];   // [D,D]
    const float* bout = (const float*)d_in[4];   // [D]
    float* out = (float*)d_out;                  // [B,T,D]

    float* qkv  = (float*)d_ws;                       // [4096][3072]  48 MB
    float* attn = qkv + (size_t)4096 * 3072;          // [4096][1024]  16 MB

    const int M = Bb * Tt;   // 4096

    // 1) qkv = x @ Wqkv + bqkv
    sgemm_bias<<<dim3(3072 / 64, M / 64), dim3(256), 0, stream>>>(
        x, Wqkv, bqkv, qkv, M, 3072, Dd);

    // 2) flash causal attention -> attn [B*T][D] (head-major cols)
    attn_kernel<<<dim3(Tt / 64, Hh, Bb), dim3(256), 0, stream>>>(qkv, attn);

    // 3) out = attn @ Wout + bout
    sgemm_bias<<<dim3(Dd / 64, M / 64), dim3(256), 0, stream>>>(
        attn, Wout, bout, out, M, Dd, Dd);
}

// Round 2
// 333.373 us; speedup vs baseline: 6.3448x; 6.3448x over previous
//
#include <hip/hip_runtime.h>
#include <hip/hip_bf16.h>

typedef __attribute__((ext_vector_type(8))) short bf16x8;   // 8 bf16 = 4 VGPRs
typedef __attribute__((ext_vector_type(4))) float f32x4;
typedef unsigned short u16;
typedef unsigned int uint;

#define Bb 2
#define Tt 2048
#define Dd 1024
#define Hh 16

__device__ inline u16 f2bf(float f) {
    union { float f; uint u; } v; v.f = f;
    uint r = v.u + 0x7fffu + ((v.u >> 16) & 1u);   // RNE
    return (u16)(r >> 16);
}

// ---------------------------------------------------------------------------
// fp32 -> bf16 elementwise (8 elems/thread)
// ---------------------------------------------------------------------------
__global__ __launch_bounds__(256) void cvt_bf16(
    const float* __restrict__ in, u16* __restrict__ out)
{
    const size_t i = ((size_t)blockIdx.x * 256 + threadIdx.x) * 8;
    const float4 a = *(const float4*)&in[i];
    const float4 b = *(const float4*)&in[i + 4];
    uint4 o;
    o.x = (uint)f2bf(a.x) | ((uint)f2bf(a.y) << 16);
    o.y = (uint)f2bf(a.z) | ((uint)f2bf(a.w) << 16);
    o.z = (uint)f2bf(b.x) | ((uint)f2bf(b.y) << 16);
    o.w = (uint)f2bf(b.z) | ((uint)f2bf(b.w) << 16);
    *(uint4*)&out[i] = o;
}

// ---------------------------------------------------------------------------
// W[K][N] fp32 -> Wt[N][K] bf16, 64x64 LDS tile
// ---------------------------------------------------------------------------
__global__ __launch_bounds__(256) void transpose_cvt(
    const float* __restrict__ W, u16* __restrict__ Wt, int K, int N)
{
    __shared__ float tile[64][65];
    const int k0 = blockIdx.y * 64, n0 = blockIdx.x * 64;
    const int tid = threadIdx.x;
    const int tr = tid >> 4;           // 0..15
    const int tc = (tid & 15) * 4;     // 0..60

    #pragma unroll
    for (int i = 0; i < 4; ++i) {
        const float4 v = *(const float4*)&W[(size_t)(k0 + tr + i * 16) * N + n0 + tc];
        tile[tr + i * 16][tc + 0] = v.x;
        tile[tr + i * 16][tc + 1] = v.y;
        tile[tr + i * 16][tc + 2] = v.z;
        tile[tr + i * 16][tc + 3] = v.w;
    }
    __syncthreads();
    #pragma unroll
    for (int i = 0; i < 4; ++i) {
        ushort4 o;
        o.x = f2bf(tile[tc + 0][tr + i * 16]);
        o.y = f2bf(tile[tc + 1][tr + i * 16]);
        o.z = f2bf(tile[tc + 2][tr + i * 16]);
        o.w = f2bf(tile[tc + 3][tr + i * 16]);
        *(ushort4*)&Wt[(size_t)(n0 + tr + i * 16) * K + k0 + tc] = o;
    }
}

// ---------------------------------------------------------------------------
// C[M][N] = A[M][K] @ Bt[N][K]^T + bias, bf16 MFMA.
// 128x128 tile, 256 threads = 4 waves (2x2), each wave 64x64 = 4x4 MFMA tiles.
// BK=32 (one 16x16x32 MFMA k-step). LDS row stride 40 halves (80 B: 16-aligned,
// banks spread; see bank math in session notes).
// ---------------------------------------------------------------------------
template <int OUT_BF16>
__global__ __launch_bounds__(256) void gemm_bt(
    const u16* __restrict__ A, const u16* __restrict__ Bt,
    const float* __restrict__ bias, void* __restrict__ C,
    int M, int N, int K)
{
    __shared__ u16 As[128 * 40];
    __shared__ u16 Bs[128 * 40];

    const int tid  = threadIdx.x;
    const int lane = tid & 63;
    const int w    = tid >> 6;
    const int wm   = w >> 1, wn = w & 1;
    const int quad = lane >> 4;
    const int m16  = lane & 15;
    const int row0 = blockIdx.y * 128;
    const int col0 = blockIdx.x * 128;

    f32x4 acc[4][4];
    #pragma unroll
    for (int i = 0; i < 4; ++i)
        #pragma unroll
        for (int j = 0; j < 4; ++j) acc[i][j] = (f32x4){0.f, 0.f, 0.f, 0.f};

    // staging: 512 16B-chunks per 128x32 tile; chunk ci -> row=ci>>2, kc=ci&3
    const int r0s = tid >> 2,        k0s = tid & 3;
    const int r1s = (tid + 256) >> 2, k1s = tid & 3;   // +256 => row+64, same kc

    for (int ko = 0; ko < K; ko += 32) {
        const int4 va0 = *(const int4*)&A [(size_t)(row0 + r0s) * K + ko + k0s * 8];
        const int4 va1 = *(const int4*)&A [(size_t)(row0 + r1s) * K + ko + k1s * 8];
        const int4 vb0 = *(const int4*)&Bt[(size_t)(col0 + r0s) * K + ko + k0s * 8];
        const int4 vb1 = *(const int4*)&Bt[(size_t)(col0 + r1s) * K + ko + k1s * 8];
        __syncthreads();   // previous iteration's frag reads done
        *(int4*)&As[r0s * 40 + k0s * 8] = va0;
        *(int4*)&As[r1s * 40 + k1s * 8] = va1;
        *(int4*)&Bs[r0s * 40 + k0s * 8] = vb0;
        *(int4*)&Bs[r1s * 40 + k1s * 8] = vb1;
        __syncthreads();

        bf16x8 af[4], bfr[4];
        #pragma unroll
        for (int mt = 0; mt < 4; ++mt)
            af[mt] = *(const bf16x8*)&As[(wm * 64 + mt * 16 + m16) * 40 + quad * 8];
        #pragma unroll
        for (int nt = 0; nt < 4; ++nt)
            bfr[nt] = *(const bf16x8*)&Bs[(wn * 64 + nt * 16 + m16) * 40 + quad * 8];
        #pragma unroll
        for (int mt = 0; mt < 4; ++mt)
            #pragma unroll
            for (int nt = 0; nt < 4; ++nt)
                acc[mt][nt] = __builtin_amdgcn_mfma_f32_16x16x32_bf16(
                    af[mt], bfr[nt], acc[mt][nt], 0, 0, 0);
    }

    // epilogue: C row = row0+wm*64+mt*16+quad*4+r, col = col0+wn*64+nt*16+m16
    #pragma unroll
    for (int mt = 0; mt < 4; ++mt) {
        #pragma unroll
        for (int nt = 0; nt < 4; ++nt) {
            const int row = row0 + wm * 64 + mt * 16 + quad * 4;
            const int col = col0 + wn * 64 + nt * 16 + m16;
            const float bv = bias[col];
            #pragma unroll
            for (int r = 0; r < 4; ++r) {
                const float v = acc[mt][nt][r] + bv;
                if (OUT_BF16)
                    ((u16*)C)[(size_t)(row + r) * N + col] = f2bf(v);
                else
                    ((float*)C)[(size_t)(row + r) * N + col] = v;
            }
        }
    }
}

// ---------------------------------------------------------------------------
// Flash causal attention, bf16 MFMA. One block per (qt, h, b); 4 waves, each
// owns 16 q-rows. qkv bf16 [B*T][3072]; out bf16 [B*T][1024] head-major cols.
// LDS stride 72 halves (144 B, 16-aligned). V staged transposed: Vt[d][key].
// ---------------------------------------------------------------------------
__global__ __launch_bounds__(256) void attn_mfma(
    const u16* __restrict__ qkv, u16* __restrict__ attn_out)
{
    const int qt  = blockIdx.x;
    const int h   = blockIdx.y;
    const int b   = blockIdx.z;
    const int tid = threadIdx.x;
    const int lane = tid & 63, w = tid >> 6;
    const int quad = lane >> 4, m16 = lane & 15;

    __shared__ u16 Qs[64 * 72];
    __shared__ u16 Ks[64 * 72];
    __shared__ u16 Vt[64 * 72];
    __shared__ u16 Ps[64 * 72];

    const int q0 = qt * 64;
    const size_t base = (size_t)(b * Tt) * 3072;

    // stage Q: 512 16B-chunks; ci -> row=ci>>3, kc=ci&7
    #pragma unroll
    for (int j = 0; j < 2; ++j) {
        const int ci = tid + j * 256;
        const int row = ci >> 3, kc = ci & 7;
        *(int4*)&Qs[row * 72 + kc * 8] =
            *(const int4*)&qkv[base + (size_t)(q0 + row) * 3072 + h * 64 + kc * 8];
    }

    f32x4 o[4];
    #pragma unroll
    for (int ct = 0; ct < 4; ++ct) o[ct] = (f32x4){0.f, 0.f, 0.f, 0.f};
    float m_prev[4], l_prev[4];
    #pragma unroll
    for (int r = 0; r < 4; ++r) { m_prev[r] = -__builtin_inff(); l_prev[r] = 0.f; }
    const float scale = 0.125f;   // 1/sqrt(64)

    for (int kt = 0; kt <= qt; ++kt) {
        const int k0 = kt * 64;
        __syncthreads();   // prev iter done with Ks/Vt/Ps (+ Q visible, iter 0)

        // stage K (copy rows) and V (transpose to Vt[d][key])
        #pragma unroll
        for (int j = 0; j < 2; ++j) {
            const int ci = tid + j * 256;
            const int row = ci >> 3, kc = ci & 7;      // row = key idx
            const size_t g = base + (size_t)(k0 + row) * 3072 + h * 64;
            *(int4*)&Ks[row * 72 + kc * 8] = *(const int4*)&qkv[g + 1024 + kc * 8];
            union { int4 v; u16 u[8]; } uv;
            uv.v = *(const int4*)&qkv[g + 2048 + kc * 8];
            #pragma unroll
            for (int e = 0; e < 8; ++e)
                Vt[(kc * 8 + e) * 72 + row] = uv.u[e];
        }
        __syncthreads();

        // S = Q K^T : wave w computes rows 16w..16w+15 x 64 keys
        const int arow = (w * 16 + m16) * 72 + quad * 8;
        const bf16x8 qf0 = *(const bf16x8*)&Qs[arow];
        const bf16x8 qf1 = *(const bf16x8*)&Qs[arow + 32];
        f32x4 s[4];
        #pragma unroll
        for (int ct = 0; ct < 4; ++ct) {
            const int brow = (ct * 16 + m16) * 72 + quad * 8;
            const bf16x8 kf0 = *(const bf16x8*)&Ks[brow];
            const bf16x8 kf1 = *(const bf16x8*)&Ks[brow + 32];
            f32x4 a = (f32x4){0.f, 0.f, 0.f, 0.f};
            a = __builtin_amdgcn_mfma_f32_16x16x32_bf16(qf0, kf0, a, 0, 0, 0);
            a = __builtin_amdgcn_mfma_f32_16x16x32_bf16(qf1, kf1, a, 0, 0, 0);
            s[ct] = a;
        }

        // online softmax in C-layout: row = 16w + quad*4 + r, col = ct*16+m16
        float mloc[4];
        #pragma unroll
        for (int r = 0; r < 4; ++r) mloc[r] = -__builtin_inff();
        #pragma unroll
        for (int ct = 0; ct < 4; ++ct) {
            const int ki = k0 + ct * 16 + m16;
            #pragma unroll
            for (int r = 0; r < 4; ++r) {
                const int qi = q0 + w * 16 + quad * 4 + r;
                const float v = (ki <= qi) ? s[ct][r] * scale : -__builtin_inff();
                s[ct][r] = v;
                mloc[r] = fmaxf(mloc[r], v);
            }
        }
        #pragma unroll
        for (int off = 1; off < 16; off <<= 1)
            #pragma unroll
            for (int r = 0; r < 4; ++r)
                mloc[r] = fmaxf(mloc[r], __shfl_xor(mloc[r], off));

        float alpha[4], lsum[4];
        #pragma unroll
        for (int r = 0; r < 4; ++r) {
            const float mn = fmaxf(m_prev[r], mloc[r]);
            alpha[r] = __expf(m_prev[r] - mn);   // first tile: exp(-inf)=0
            m_prev[r] = mn;
            lsum[r] = 0.f;
        }
        #pragma unroll
        for (int ct = 0; ct < 4; ++ct)
            #pragma unroll
            for (int r = 0; r < 4; ++r) {
                const float p = __expf(s[ct][r] - m_prev[r]);
                lsum[r] += p;
                Ps[(w * 16 + quad * 4 + r) * 72 + ct * 16 + m16] = f2bf(p);
            }
        #pragma unroll
        for (int off = 1; off < 16; off <<= 1)
            #pragma unroll
            for (int r = 0; r < 4; ++r)
                lsum[r] += __shfl_xor(lsum[r], off);
        #pragma unroll
        for (int r = 0; r < 4; ++r) l_prev[r] = l_prev[r] * alpha[r] + lsum[r];
        #pragma unroll
        for (int ct = 0; ct < 4; ++ct)
            #pragma unroll
            for (int r = 0; r < 4; ++r)
                o[ct][r] *= alpha[r];

        __syncthreads();   // Ps visible (and lgkm drained) before A-frag reads

        // O += P V : A = P rows 16w.., B = Vt (B[k=key][n=d] via Vt[d][key])
        const int prow = (w * 16 + m16) * 72 + quad * 8;
        const bf16x8 pf0 = *(const bf16x8*)&Ps[prow];
        const bf16x8 pf1 = *(const bf16x8*)&Ps[prow + 32];
        #pragma unroll
        for (int ct = 0; ct < 4; ++ct) {
            const int vrow = (ct * 16 + m16) * 72 + quad * 8;
            const bf16x8 vf0 = *(const bf16x8*)&Vt[vrow];
            const bf16x8 vf1 = *(const bf16x8*)&Vt[vrow + 32];
            o[ct] = __builtin_amdgcn_mfma_f32_16x16x32_bf16(pf0, vf0, o[ct], 0, 0, 0);
            o[ct] = __builtin_amdgcn_mfma_f32_16x16x32_bf16(pf1, vf1, o[ct], 0, 0, 0);
        }
    }

    // write O/l as bf16; row = q0+16w+quad*4+r, col = h*64+ct*16+m16
    float invl[4];
    #pragma unroll
    for (int r = 0; r < 4; ++r) invl[r] = 1.0f / l_prev[r];
    #pragma unroll
    for (int ct = 0; ct < 4; ++ct)
        #pragma unroll
        for (int r = 0; r < 4; ++r) {
            const size_t idx = (size_t)(b * Tt + q0 + w * 16 + quad * 4 + r) * 1024
                             + h * 64 + ct * 16 + m16;
            attn_out[idx] = f2bf(o[ct][r] * invl[r]);
        }
}

// ---------------------------------------------------------------------------
extern "C" void kernel_launch(void* const* d_in, const int* in_sizes, int n_in,
                              void* d_out, int out_size, void* d_ws, size_t ws_size,
                              hipStream_t stream) {
    const float* x    = (const float*)d_in[0];   // [B,T,D]
    const float* Wqkv = (const float*)d_in[1];   // [D,3D]
    const float* bqkv = (const float*)d_in[2];   // [3D]
    const float* Wout = (const float*)d_in[3];   // [D,D]
    const float* bout = (const float*)d_in[4];   // [D]
    float* out = (float*)d_out;

    u16* xb   = (u16*)d_ws;                                  //  8 MB [4096][1024]
    u16* WqT  = xb   + (size_t)4096 * 1024;                  //  6 MB [3072][1024]
    u16* WoT  = WqT  + (size_t)3072 * 1024;                  //  2 MB [1024][1024]
    u16* qkvb = WoT  + (size_t)1024 * 1024;                  // 24 MB [4096][3072]
    u16* attb = qkvb + (size_t)4096 * 3072;                  //  8 MB [4096][1024]

    cvt_bf16<<<dim3((4096 * 1024) / 8 / 256), dim3(256), 0, stream>>>(x, xb);
    transpose_cvt<<<dim3(3072 / 64, 1024 / 64), dim3(256), 0, stream>>>(Wqkv, WqT, 1024, 3072);
    transpose_cvt<<<dim3(1024 / 64, 1024 / 64), dim3(256), 0, stream>>>(Wout, WoT, 1024, 1024);

    gemm_bt<1><<<dim3(3072 / 128, 4096 / 128), dim3(256), 0, stream>>>(
        xb, WqT, bqkv, qkvb, 4096, 3072, 1024);

    attn_mfma<<<dim3(Tt / 64, Hh, Bb), dim3(256), 0, stream>>>(qkvb, attb);

    gemm_bt<0><<<dim3(1024 / 128, 4096 / 128), dim3(256), 0, stream>>>(
        attb, WoT, bout, out, 4096, 1024, 1024);
}

// Round 4
// 219.357 us; speedup vs baseline: 9.6427x; 1.5198x over previous
//
#include <hip/hip_runtime.h>
#include <hip/hip_bf16.h>

typedef __attribute__((ext_vector_type(8))) short bf16x8;   // 8 bf16 = 4 VGPRs
typedef __attribute__((ext_vector_type(4))) float f32x4;
typedef unsigned short u16;
typedef unsigned int uint;

#define Bb 2
#define Tt 2048
#define Dd 1024
#define Hh 16

__device__ inline u16 f2bf(float f) {
    union { float f; uint u; } v; v.f = f;
    uint r = v.u + 0x7fffu + ((v.u >> 16) & 1u);   // RNE
    return (u16)(r >> 16);
}

// ---------------------------------------------------------------------------
// fp32 -> bf16 elementwise (8 elems/thread)
// ---------------------------------------------------------------------------
__global__ __launch_bounds__(256) void cvt_bf16(
    const float* __restrict__ in, u16* __restrict__ out)
{
    const size_t i = ((size_t)blockIdx.x * 256 + threadIdx.x) * 8;
    const float4 a = *(const float4*)&in[i];
    const float4 b = *(const float4*)&in[i + 4];
    uint4 o;
    o.x = (uint)f2bf(a.x) | ((uint)f2bf(a.y) << 16);
    o.y = (uint)f2bf(a.z) | ((uint)f2bf(a.w) << 16);
    o.z = (uint)f2bf(b.x) | ((uint)f2bf(b.y) << 16);
    o.w = (uint)f2bf(b.z) | ((uint)f2bf(b.w) << 16);
    *(uint4*)&out[i] = o;
}

// ---------------------------------------------------------------------------
// W[K][N] fp32 -> Wt[N][K] bf16, 64x64 LDS tile
// ---------------------------------------------------------------------------
__global__ __launch_bounds__(256) void transpose_cvt(
    const float* __restrict__ W, u16* __restrict__ Wt, int K, int N)
{
    __shared__ float tile[64][65];
    const int k0 = blockIdx.y * 64, n0 = blockIdx.x * 64;
    const int tid = threadIdx.x;
    const int tr = tid >> 4;           // 0..15
    const int tc = (tid & 15) * 4;     // 0..60

    #pragma unroll
    for (int i = 0; i < 4; ++i) {
        const float4 v = *(const float4*)&W[(size_t)(k0 + tr + i * 16) * N + n0 + tc];
        tile[tr + i * 16][tc + 0] = v.x;
        tile[tr + i * 16][tc + 1] = v.y;
        tile[tr + i * 16][tc + 2] = v.z;
        tile[tr + i * 16][tc + 3] = v.w;
    }
    __syncthreads();
    #pragma unroll
    for (int i = 0; i < 4; ++i) {
        ushort4 o;
        o.x = f2bf(tile[tc + 0][tr + i * 16]);
        o.y = f2bf(tile[tc + 1][tr + i * 16]);
        o.z = f2bf(tile[tc + 2][tr + i * 16]);
        o.w = f2bf(tile[tc + 3][tr + i * 16]);
        *(ushort4*)&Wt[(size_t)(n0 + tr + i * 16) * K + k0 + tc] = o;
    }
}

// ---------------------------------------------------------------------------
// V part of qkvb [B*T][3072] (cols 2048..3071, head-major) -> Vt[b][h][d][T]
// 64x64 u16 LDS-tiled transpose.
// ---------------------------------------------------------------------------
__global__ __launch_bounds__(256) void vtrans(
    const u16* __restrict__ qkvb, u16* __restrict__ vglob)
{
    __shared__ u16 ts[64 * 72];
    const int tt = blockIdx.x;           // t-tile 0..31
    const int hb = blockIdx.y;           // 0..31
    const int h = hb & 15, b = hb >> 4;
    const int tid = threadIdx.x;
    const int t0 = tt * 64;
    const size_t vbase = (size_t)((b * Hh + h) * 64) * Tt;

    #pragma unroll
    for (int j = 0; j < 2; ++j) {
        const int ci = tid + j * 256;
        const int t = ci >> 3, dc = ci & 7;
        *(int4*)&ts[t * 72 + dc * 8] =
            *(const int4*)&qkvb[(size_t)(b * Tt + t0 + t) * 3072 + 2048 + h * 64 + dc * 8];
    }
    __syncthreads();
    #pragma unroll
    for (int j = 0; j < 2; ++j) {
        const int ci = tid + j * 256;
        const int d = ci >> 3, tc = ci & 7;
        ushort4 lo, hi;
        lo.x = ts[(tc * 8 + 0) * 72 + d];
        lo.y = ts[(tc * 8 + 1) * 72 + d];
        lo.z = ts[(tc * 8 + 2) * 72 + d];
        lo.w = ts[(tc * 8 + 3) * 72 + d];
        hi.x = ts[(tc * 8 + 4) * 72 + d];
        hi.y = ts[(tc * 8 + 5) * 72 + d];
        hi.z = ts[(tc * 8 + 6) * 72 + d];
        hi.w = ts[(tc * 8 + 7) * 72 + d];
        *(ushort4*)&vglob[vbase + (size_t)d * Tt + t0 + tc * 8] = lo;
        *(ushort4*)&vglob[vbase + (size_t)d * Tt + t0 + tc * 8 + 4] = hi;
    }
}

// ---------------------------------------------------------------------------
// C[M][N] = A[M][K] @ Bt[N][K]^T + bias, bf16 MFMA. (unchanged)
// ---------------------------------------------------------------------------
template <int OUT_BF16>
__global__ __launch_bounds__(256) void gemm_bt(
    const u16* __restrict__ A, const u16* __restrict__ Bt,
    const float* __restrict__ bias, void* __restrict__ C,
    int M, int N, int K)
{
    __shared__ u16 As[128 * 40];
    __shared__ u16 Bs[128 * 40];

    const int tid  = threadIdx.x;
    const int lane = tid & 63;
    const int w    = tid >> 6;
    const int wm   = w >> 1, wn = w & 1;
    const int quad = lane >> 4;
    const int m16  = lane & 15;
    const int row0 = blockIdx.y * 128;
    const int col0 = blockIdx.x * 128;

    f32x4 acc[4][4];
    #pragma unroll
    for (int i = 0; i < 4; ++i)
        #pragma unroll
        for (int j = 0; j < 4; ++j) acc[i][j] = (f32x4){0.f, 0.f, 0.f, 0.f};

    const int r0s = tid >> 2,         k0s = tid & 3;
    const int r1s = (tid + 256) >> 2, k1s = tid & 3;

    for (int ko = 0; ko < K; ko += 32) {
        const int4 va0 = *(const int4*)&A [(size_t)(row0 + r0s) * K + ko + k0s * 8];
        const int4 va1 = *(const int4*)&A [(size_t)(row0 + r1s) * K + ko + k1s * 8];
        const int4 vb0 = *(const int4*)&Bt[(size_t)(col0 + r0s) * K + ko + k0s * 8];
        const int4 vb1 = *(const int4*)&Bt[(size_t)(col0 + r1s) * K + ko + k1s * 8];
        __syncthreads();
        *(int4*)&As[r0s * 40 + k0s * 8] = va0;
        *(int4*)&As[r1s * 40 + k1s * 8] = va1;
        *(int4*)&Bs[r0s * 40 + k0s * 8] = vb0;
        *(int4*)&Bs[r1s * 40 + k1s * 8] = vb1;
        __syncthreads();

        bf16x8 af[4], bfr[4];
        #pragma unroll
        for (int mt = 0; mt < 4; ++mt)
            af[mt] = *(const bf16x8*)&As[(wm * 64 + mt * 16 + m16) * 40 + quad * 8];
        #pragma unroll
        for (int nt = 0; nt < 4; ++nt)
            bfr[nt] = *(const bf16x8*)&Bs[(wn * 64 + nt * 16 + m16) * 40 + quad * 8];
        #pragma unroll
        for (int mt = 0; mt < 4; ++mt)
            #pragma unroll
            for (int nt = 0; nt < 4; ++nt)
                acc[mt][nt] = __builtin_amdgcn_mfma_f32_16x16x32_bf16(
                    af[mt], bfr[nt], acc[mt][nt], 0, 0, 0);
    }

    #pragma unroll
    for (int mt = 0; mt < 4; ++mt) {
        #pragma unroll
        for (int nt = 0; nt < 4; ++nt) {
            const int row = row0 + wm * 64 + mt * 16 + quad * 4;
            const int col = col0 + wn * 64 + nt * 16 + m16;
            const float bv = bias[col];
            #pragma unroll
            for (int r = 0; r < 4; ++r) {
                const float v = acc[mt][nt][r] + bv;
                if (OUT_BF16)
                    ((u16*)C)[(size_t)(row + r) * N + col] = f2bf(v);
                else
                    ((float*)C)[(size_t)(row + r) * N + col] = v;
            }
        }
    }
}

// ---------------------------------------------------------------------------
// Flash causal attention v3 (fixed epilogue): S^T = K·Q^T, 128 q-rows/block.
// ---------------------------------------------------------------------------
__global__ __launch_bounds__(256) void attn_mfma(
    const u16* __restrict__ qkvb, const u16* __restrict__ vglob,
    u16* __restrict__ attn_out)
{
    const int hb  = blockIdx.x;
    const int h   = hb & 15, b = hb >> 4;
    const int qt  = 15 - blockIdx.y;     // heavy blocks dispatched first
    const int tid = threadIdx.x;
    const int lane = tid & 63, w = tid >> 6;
    const int quad = lane >> 4, m16 = lane & 15;

    __shared__ u16 S[20480];             // 40 KiB -> 4 blocks/CU
    u16* Ks = S;                         // [64][72]
    u16* Vt = S + 4608;                  // [64][72]
    u16* Pt = S + 10240;                 // [128][80]
    u16* Ob = S;                         // [128][80] (overlays Ks+Vt, < Pt)

    const int q0 = qt * 128;
    const size_t qkbase = (size_t)(b * Tt) * 3072;
    const size_t vbase  = (size_t)((b * Hh + h) * 64) * Tt;

    // Q^T B-fragments, loop-invariant, straight from global (16B/lane):
    bf16x8 qb[2][2];
    #pragma unroll
    for (int nt = 0; nt < 2; ++nt)
        #pragma unroll
        for (int ks = 0; ks < 2; ++ks)
            qb[nt][ks] = *(const bf16x8*)&qkvb[
                qkbase + (size_t)(q0 + w * 32 + nt * 16 + m16) * 3072
                + h * 64 + ks * 32 + quad * 8];

    f32x4 o[4][2];   // O^T acc: [d-tile ct][q-tile nt]; col=q=m16, row=4quad+r
    #pragma unroll
    for (int ct = 0; ct < 4; ++ct)
        #pragma unroll
        for (int nt = 0; nt < 2; ++nt) o[ct][nt] = (f32x4){0.f, 0.f, 0.f, 0.f};
    float mst[2] = {-__builtin_inff(), -__builtin_inff()};
    float lst[2] = {0.f, 0.f};
    const float scale = 0.125f;

    const int ntiles = 2 * qt + 2;
    for (int kt = 0; kt < ntiles; ++kt) {
        const int k0 = kt * 64;
        __syncthreads();   // prior tile's frag reads complete before restage
        #pragma unroll
        for (int j = 0; j < 2; ++j) {
            const int ci = tid + j * 256;
            const int row = ci >> 3, kc = ci & 7;
            *(int4*)&Ks[row * 72 + kc * 8] = *(const int4*)&qkvb[
                qkbase + (size_t)(k0 + row) * 3072 + 1024 + h * 64 + kc * 8];
            *(int4*)&Vt[row * 72 + kc * 8] = *(const int4*)&vglob[
                vbase + (size_t)row * Tt + k0 + kc * 8];
        }
        __syncthreads();

        if (k0 <= q0 + w * 32 + 31) {    // wave-uniform: tile visible
            // S^T = K · Q^T : A = K rows (Ks), B = Q^T (regs)
            bf16x8 ak[4][2];
            #pragma unroll
            for (int mt = 0; mt < 4; ++mt)
                #pragma unroll
                for (int ks = 0; ks < 2; ++ks)
                    ak[mt][ks] = *(const bf16x8*)&Ks[(mt * 16 + m16) * 72 + ks * 32 + quad * 8];
            f32x4 s[4][2];
            #pragma unroll
            for (int mt = 0; mt < 4; ++mt)
                #pragma unroll
                for (int nt = 0; nt < 2; ++nt) {
                    f32x4 a = (f32x4){0.f, 0.f, 0.f, 0.f};
                    a = __builtin_amdgcn_mfma_f32_16x16x32_bf16(ak[mt][0], qb[nt][0], a, 0, 0, 0);
                    a = __builtin_amdgcn_mfma_f32_16x16x32_bf16(ak[mt][1], qb[nt][1], a, 0, 0, 0);
                    s[mt][nt] = a;
                }

            // scale (+ mask only on diagonal-crossing tiles, wave-uniform)
            const int qi0 = q0 + w * 32 + m16;   // nt=0 q; nt=1 adds 16
            if (k0 + 63 > q0 + w * 32) {
                #pragma unroll
                for (int mt = 0; mt < 4; ++mt)
                    #pragma unroll
                    for (int nt = 0; nt < 2; ++nt)
                        #pragma unroll
                        for (int r = 0; r < 4; ++r) {
                            const int key = k0 + mt * 16 + quad * 4 + r;
                            const float v = s[mt][nt][r] * scale;
                            s[mt][nt][r] = (key <= qi0 + nt * 16) ? v : -__builtin_inff();
                        }
            } else {
                #pragma unroll
                for (int mt = 0; mt < 4; ++mt)
                    #pragma unroll
                    for (int nt = 0; nt < 2; ++nt)
                        #pragma unroll
                        for (int r = 0; r < 4; ++r)
                            s[mt][nt][r] *= scale;
            }

            // online softmax: per lane one q per nt; reduce across quads only
            float mx[2] = {-__builtin_inff(), -__builtin_inff()};
            #pragma unroll
            for (int mt = 0; mt < 4; ++mt)
                #pragma unroll
                for (int nt = 0; nt < 2; ++nt)
                    #pragma unroll
                    for (int r = 0; r < 4; ++r)
                        mx[nt] = fmaxf(mx[nt], s[mt][nt][r]);
            #pragma unroll
            for (int nt = 0; nt < 2; ++nt) {
                mx[nt] = fmaxf(mx[nt], __shfl_xor(mx[nt], 16));
                mx[nt] = fmaxf(mx[nt], __shfl_xor(mx[nt], 32));
            }
            float al[2], ls[2];
            #pragma unroll
            for (int nt = 0; nt < 2; ++nt) {
                const float mn = fmaxf(mst[nt], mx[nt]);
                al[nt] = __expf(mst[nt] - mn);
                mst[nt] = mn;
                ls[nt] = 0.f;
            }
            #pragma unroll
            for (int mt = 0; mt < 4; ++mt)
                #pragma unroll
                for (int nt = 0; nt < 2; ++nt) {
                    ushort4 pk;
                    float p0 = __expf(s[mt][nt][0] - mst[nt]);
                    float p1 = __expf(s[mt][nt][1] - mst[nt]);
                    float p2 = __expf(s[mt][nt][2] - mst[nt]);
                    float p3 = __expf(s[mt][nt][3] - mst[nt]);
                    ls[nt] += (p0 + p1) + (p2 + p3);
                    pk.x = f2bf(p0); pk.y = f2bf(p1); pk.z = f2bf(p2); pk.w = f2bf(p3);
                    // P^T[key][q] stored as Pt[q][key]: 4 consecutive keys -> b64
                    *(ushort4*)&Pt[(w * 32 + nt * 16 + m16) * 80 + mt * 16 + quad * 4] = pk;
                }
            #pragma unroll
            for (int nt = 0; nt < 2; ++nt) {
                ls[nt] += __shfl_xor(ls[nt], 16);
                ls[nt] += __shfl_xor(ls[nt], 32);
                lst[nt] = lst[nt] * al[nt] + ls[nt];
            }
            #pragma unroll
            for (int ct = 0; ct < 4; ++ct)
                #pragma unroll
                for (int nt = 0; nt < 2; ++nt)
                    #pragma unroll
                    for (int r = 0; r < 4; ++r)
                        o[ct][nt][r] *= al[nt];

            // O^T += V^T · P^T : A = Vt rows (d-major), B = Pt rows (q-major)
            bf16x8 av[4][2], pb[2][2];
            #pragma unroll
            for (int ct = 0; ct < 4; ++ct)
                #pragma unroll
                for (int ks = 0; ks < 2; ++ks)
                    av[ct][ks] = *(const bf16x8*)&Vt[(ct * 16 + m16) * 72 + ks * 32 + quad * 8];
            #pragma unroll
            for (int nt = 0; nt < 2; ++nt)
                #pragma unroll
                for (int ks = 0; ks < 2; ++ks)
                    pb[nt][ks] = *(const bf16x8*)&Pt[(w * 32 + nt * 16 + m16) * 80 + ks * 32 + quad * 8];
            #pragma unroll
            for (int ct = 0; ct < 4; ++ct)
                #pragma unroll
                for (int nt = 0; nt < 2; ++nt) {
                    o[ct][nt] = __builtin_amdgcn_mfma_f32_16x16x32_bf16(av[ct][0], pb[nt][0], o[ct][nt], 0, 0, 0);
                    o[ct][nt] = __builtin_amdgcn_mfma_f32_16x16x32_bf16(av[ct][1], pb[nt][1], o[ct][nt], 0, 0, 0);
                }
        }
    }

    // epilogue: O^T -> Ob[q][d] (transpose via b64 packs), then coalesced store
    float invl[2];
    invl[0] = 1.0f / lst[0];
    invl[1] = 1.0f / lst[1];
    __syncthreads();   // all waves done reading Ks/Vt before Ob overlays them
    #pragma unroll
    for (int ct = 0; ct < 4; ++ct)
        #pragma unroll
        for (int nt = 0; nt < 2; ++nt) {
            ushort4 pk;   // rows d = 16ct + 4quad + r, col q = 16nt + m16
            pk.x = f2bf(o[ct][nt][0] * invl[nt]);
            pk.y = f2bf(o[ct][nt][1] * invl[nt]);
            pk.z = f2bf(o[ct][nt][2] * invl[nt]);
            pk.w = f2bf(o[ct][nt][3] * invl[nt]);
            *(ushort4*)&Ob[(w * 32 + nt * 16 + m16) * 80 + ct * 16 + quad * 4] = pk;
        }
    __syncthreads();
    // 128 rows x 8 chunks = 1024 int4 chunks -> 4 iterations of 256 threads
    #pragma unroll
    for (int j = 0; j < 4; ++j) {
        const int ci = tid + j * 256;
        const int q = ci >> 3, kc = ci & 7;
        const int4 v = *(const int4*)&Ob[q * 80 + kc * 8];
        *(int4*)&attn_out[(size_t)(b * Tt + q0 + q) * 1024 + h * 64 + kc * 8] = v;
    }
}

// ---------------------------------------------------------------------------
extern "C" void kernel_launch(void* const* d_in, const int* in_sizes, int n_in,
                              void* d_out, int out_size, void* d_ws, size_t ws_size,
                              hipStream_t stream) {
    const float* x    = (const float*)d_in[0];
    const float* Wqkv = (const float*)d_in[1];
    const float* bqkv = (const float*)d_in[2];
    const float* Wout = (const float*)d_in[3];
    const float* bout = (const float*)d_in[4];
    float* out = (float*)d_out;

    u16* xb    = (u16*)d_ws;                                 //  8 MB [4096][1024]
    u16* WqT   = xb    + (size_t)4096 * 1024;                //  6 MB [3072][1024]
    u16* WoT   = WqT   + (size_t)3072 * 1024;                //  2 MB [1024][1024]
    u16* qkvb  = WoT   + (size_t)1024 * 1024;                // 24 MB [4096][3072]
    u16* attb  = qkvb  + (size_t)4096 * 3072;                //  8 MB [4096][1024]
    u16* vglob = attb  + (size_t)4096 * 1024;                //  8 MB [2][16][64][2048]

    cvt_bf16<<<dim3((4096 * 1024) / 8 / 256), dim3(256), 0, stream>>>(x, xb);
    transpose_cvt<<<dim3(3072 / 64, 1024 / 64), dim3(256), 0, stream>>>(Wqkv, WqT, 1024, 3072);
    transpose_cvt<<<dim3(1024 / 64, 1024 / 64), dim3(256), 0, stream>>>(Wout, WoT, 1024, 1024);

    gemm_bt<1><<<dim3(3072 / 128, 4096 / 128), dim3(256), 0, stream>>>(
        xb, WqT, bqkv, qkvb, 4096, 3072, 1024);

    vtrans<<<dim3(Tt / 64, Hh * Bb), dim3(256), 0, stream>>>(qkvb, vglob);

    attn_mfma<<<dim3(Hh * Bb, Tt / 128), dim3(256), 0, stream>>>(qkvb, vglob, attb);

    gemm_bt<0><<<dim3(1024 / 128, 4096 / 128), dim3(256), 0, stream>>>(
        attb, WoT, bout, out, 4096, 1024, 1024);
}

// Round 7
// 218.664 us; speedup vs baseline: 9.6732x; 1.0032x over previous
//
#include <hip/hip_runtime.h>
#include <hip/hip_bf16.h>

typedef __attribute__((ext_vector_type(8))) short bf16x8;   // 8 bf16 = 4 VGPRs
typedef __attribute__((ext_vector_type(4))) float f32x4;
typedef unsigned short u16;
typedef unsigned int uint;

#define Bb 2
#define Tt 2048
#define Dd 1024
#define Hh 16

__device__ inline u16 f2bf(float f) {
    union { float f; uint u; } v; v.f = f;
    uint r = v.u + 0x7fffu + ((v.u >> 16) & 1u);   // RNE
    return (u16)(r >> 16);
}

// async global->LDS, 16B per lane. Dest must be wave-uniform base; HW adds
// lane*16. [m97 pattern: emits global_load_lds_dwordx4]
__device__ inline void glds16(const u16* g, u16* l) {
    __builtin_amdgcn_global_load_lds(
        (const __attribute__((address_space(1))) void*)g,
        (__attribute__((address_space(3))) void*)l,
        16, 0, 0);
}

// ---------------------------------------------------------------------------
// fp32 -> bf16 elementwise (8 elems/thread)
// ---------------------------------------------------------------------------
__global__ __launch_bounds__(256) void cvt_bf16(
    const float* __restrict__ in, u16* __restrict__ out)
{
    const size_t i = ((size_t)blockIdx.x * 256 + threadIdx.x) * 8;
    const float4 a = *(const float4*)&in[i];
    const float4 b = *(const float4*)&in[i + 4];
    uint4 o;
    o.x = (uint)f2bf(a.x) | ((uint)f2bf(a.y) << 16);
    o.y = (uint)f2bf(a.z) | ((uint)f2bf(a.w) << 16);
    o.z = (uint)f2bf(b.x) | ((uint)f2bf(b.y) << 16);
    o.w = (uint)f2bf(b.z) | ((uint)f2bf(b.w) << 16);
    *(uint4*)&out[i] = o;
}

// ---------------------------------------------------------------------------
// W[K][N] fp32 -> Wt[N][K] bf16, 64x64 LDS tile
// ---------------------------------------------------------------------------
__global__ __launch_bounds__(256) void transpose_cvt(
    const float* __restrict__ W, u16* __restrict__ Wt, int K, int N)
{
    __shared__ float tile[64][65];
    const int k0 = blockIdx.y * 64, n0 = blockIdx.x * 64;
    const int tid = threadIdx.x;
    const int tr = tid >> 4;           // 0..15
    const int tc = (tid & 15) * 4;     // 0..60

    #pragma unroll
    for (int i = 0; i < 4; ++i) {
        const float4 v = *(const float4*)&W[(size_t)(k0 + tr + i * 16) * N + n0 + tc];
        tile[tr + i * 16][tc + 0] = v.x;
        tile[tr + i * 16][tc + 1] = v.y;
        tile[tr + i * 16][tc + 2] = v.z;
        tile[tr + i * 16][tc + 3] = v.w;
    }
    __syncthreads();
    #pragma unroll
    for (int i = 0; i < 4; ++i) {
        ushort4 o;
        o.x = f2bf(tile[tc + 0][tr + i * 16]);
        o.y = f2bf(tile[tc + 1][tr + i * 16]);
        o.z = f2bf(tile[tc + 2][tr + i * 16]);
        o.w = f2bf(tile[tc + 3][tr + i * 16]);
        *(ushort4*)&Wt[(size_t)(n0 + tr + i * 16) * K + k0 + tc] = o;
    }
}

// ---------------------------------------------------------------------------
// V part of qkvb [B*T][3072] (cols 2048..3071, head-major) -> Vt[b][h][d][T]
// ---------------------------------------------------------------------------
__global__ __launch_bounds__(256) void vtrans(
    const u16* __restrict__ qkvb, u16* __restrict__ vglob)
{
    __shared__ u16 ts[64 * 72];
    const int tt = blockIdx.x;           // t-tile 0..31
    const int hb = blockIdx.y;           // 0..31
    const int h = hb & 15, b = hb >> 4;
    const int tid = threadIdx.x;
    const int t0 = tt * 64;
    const size_t vbase = (size_t)((b * Hh + h) * 64) * Tt;

    #pragma unroll
    for (int j = 0; j < 2; ++j) {
        const int ci = tid + j * 256;
        const int t = ci >> 3, dc = ci & 7;
        *(int4*)&ts[t * 72 + dc * 8] =
            *(const int4*)&qkvb[(size_t)(b * Tt + t0 + t) * 3072 + 2048 + h * 64 + dc * 8];
    }
    __syncthreads();
    #pragma unroll
    for (int j = 0; j < 2; ++j) {
        const int ci = tid + j * 256;
        const int d = ci >> 3, tc = ci & 7;
        ushort4 lo, hi;
        lo.x = ts[(tc * 8 + 0) * 72 + d];
        lo.y = ts[(tc * 8 + 1) * 72 + d];
        lo.z = ts[(tc * 8 + 2) * 72 + d];
        lo.w = ts[(tc * 8 + 3) * 72 + d];
        hi.x = ts[(tc * 8 + 4) * 72 + d];
        hi.y = ts[(tc * 8 + 5) * 72 + d];
        hi.z = ts[(tc * 8 + 6) * 72 + d];
        hi.w = ts[(tc * 8 + 7) * 72 + d];
        *(ushort4*)&vglob[vbase + (size_t)d * Tt + t0 + tc * 8] = lo;
        *(ushort4*)&vglob[vbase + (size_t)d * Tt + t0 + tc * 8 + 4] = hi;
    }
}

// ---------------------------------------------------------------------------
// C[M][N] = A[M][K] @ Bt[N][K]^T + bias, bf16 MFMA, m97 pattern:
// global_load_lds width=16, unpadded stride-32 tiles, XOR source swizzle.
// LDS chunk (r, qs) holds global k-chunk (qs ^ ((r>>1)&3)) -> frag reads are
// 2-way-aliased only (free, m136).
// ---------------------------------------------------------------------------
template <int OUT_BF16>
__global__ __launch_bounds__(256) void gemm_bt(
    const u16* __restrict__ A, const u16* __restrict__ Bt,
    const float* __restrict__ bias, void* __restrict__ C,
    int M, int N, int K)
{
    __shared__ u16 As[128 * 32];
    __shared__ u16 Bs[128 * 32];

    const int tid  = threadIdx.x;
    const int lane = tid & 63;
    const int w    = tid >> 6;
    const int wm   = w >> 1, wn = w & 1;
    const int quad = lane >> 4;
    const int m16  = lane & 15;
    const int row0 = blockIdx.y * 128;
    const int col0 = blockIdx.x * 128;

    f32x4 acc[4][4];
    #pragma unroll
    for (int i = 0; i < 4; ++i)
        #pragma unroll
        for (int j = 0; j < 4; ++j) acc[i][j] = (f32x4){0.f, 0.f, 0.f, 0.f};

    // staging: chunk ci covers (row r = ci>>2, slot qs = ci&3), fetches global
    // k-chunk q = qs ^ ((r>>1)&3). ci = tid (+256 => row+64, same xor).
    const int sr  = tid >> 2, sqs = tid & 3;
    const int sq  = sqs ^ ((sr >> 1) & 3);
    const int ldsw = w * 512;                 // u16: wave-uniform dest base
    const int slot = quad ^ ((m16 >> 1) & 3); // frag read slot (mt-independent)

    for (int ko = 0; ko < K; ko += 32) {
        __syncthreads();   // prev iter frag reads done
        glds16(&A [(size_t)(row0 + sr) * K + ko + sq * 8],       &As[ldsw]);
        glds16(&A [(size_t)(row0 + sr + 64) * K + ko + sq * 8],  &As[2048 + ldsw]);
        glds16(&Bt[(size_t)(col0 + sr) * K + ko + sq * 8],       &Bs[ldsw]);
        glds16(&Bt[(size_t)(col0 + sr + 64) * K + ko + sq * 8],  &Bs[2048 + ldsw]);
        __syncthreads();   // vmcnt(0) drain -> tiles visible

        bf16x8 af[4], bfr[4];
        #pragma unroll
        for (int mt = 0; mt < 4; ++mt)
            af[mt] = *(const bf16x8*)&As[(wm * 64 + mt * 16 + m16) * 32 + slot * 8];
        #pragma unroll
        for (int nt = 0; nt < 4; ++nt)
            bfr[nt] = *(const bf16x8*)&Bs[(wn * 64 + nt * 16 + m16) * 32 + slot * 8];
        #pragma unroll
        for (int mt = 0; mt < 4; ++mt)
            #pragma unroll
            for (int nt = 0; nt < 4; ++nt)
                acc[mt][nt] = __builtin_amdgcn_mfma_f32_16x16x32_bf16(
                    af[mt], bfr[nt], acc[mt][nt], 0, 0, 0);
    }

    #pragma unroll
    for (int mt = 0; mt < 4; ++mt) {
        #pragma unroll
        for (int nt = 0; nt < 4; ++nt) {
            const int row = row0 + wm * 64 + mt * 16 + quad * 4;
            const int col = col0 + wn * 64 + nt * 16 + m16;
            const float bv = bias[col];
            #pragma unroll
            for (int r = 0; r < 4; ++r) {
                const float v = acc[mt][nt][r] + bv;
                if (OUT_BF16)
                    ((u16*)C)[(size_t)(row + r) * N + col] = f2bf(v);
                else
                    ((float*)C)[(size_t)(row + r) * N + col] = v;
            }
        }
    }
}

// ---------------------------------------------------------------------------
// Flash causal attention v5: single-barrier double-buffered glds prefetch,
// FULL 64x64 K/V tiles (bug in v4: half-staged). S^T = K·Q^T, 128 q-rows per
// block, 4 waves x 32 rows. Tile rows stride 64 u16, XOR slot swizzle
// rho(r) = r&7 (read slot = quad ^ (m16&7); ks=1 -> ^4). Pt stride 72.
// LDS = 32 KB KV + 18 KB Pt = 50 KB -> 3 blocks/CU.
// ---------------------------------------------------------------------------
__global__ __launch_bounds__(256) void attn_mfma(
    const u16* __restrict__ qkvb, const u16* __restrict__ vglob,
    u16* __restrict__ attn_out)
{
    const int hb  = blockIdx.x;
    const int h   = hb & 15, b = hb >> 4;
    const int qt  = 15 - blockIdx.y;     // heavy blocks dispatched first
    const int tid = threadIdx.x;
    const int lane = tid & 63, w = tid >> 6;
    const int quad = lane >> 4, m16 = lane & 15;

    __shared__ u16 KV[2][2][64 * 64];    // [buf][0=K,1=Vt], full tiles, 32 KB
    __shared__ u16 Pt[128 * 72];         // P^T rows; Ob overlay in epilogue

    const int q0 = qt * 128;
    const size_t qkbase = (size_t)(b * Tt) * 3072;
    const size_t vbase  = (size_t)((b * Hh + h) * 64) * Tt;

    // staging: call j stages rows j*32 + (tid>>3); lane slot = tid&7 holds
    // global d-chunk sq8 = (tid&7) ^ ((tid>>3)&7)   [rho(row) = row&7]
    const int sr8 = tid >> 3;
    const int sq8 = (tid & 7) ^ (sr8 & 7);
    const int ldsw = w * 512;                // wave-uniform dest base (u16)
    const int slot = quad ^ (m16 & 7);       // frag read slot, ks=0

    // Q^T B-frags, loop-invariant, from global (16B/lane):
    bf16x8 qb[2][2];
    #pragma unroll
    for (int nt = 0; nt < 2; ++nt)
        #pragma unroll
        for (int ks = 0; ks < 2; ++ks)
            qb[nt][ks] = *(const bf16x8*)&qkvb[
                qkbase + (size_t)(q0 + w * 32 + nt * 16 + m16) * 3072
                + h * 64 + ks * 32 + quad * 8];

    // prologue: stage tile 0 into buf 0 (2 calls per tensor = full 64x64)
    #pragma unroll
    for (int j = 0; j < 2; ++j) {
        const int row = j * 32 + sr8;
        glds16(&qkvb[qkbase + (size_t)row * 3072 + 1024 + h * 64 + sq8 * 8],
               &KV[0][0][j * 2048 + ldsw]);
        glds16(&vglob[vbase + (size_t)row * Tt + sq8 * 8],
               &KV[0][1][j * 2048 + ldsw]);
    }

    f32x4 o[4][2];
    #pragma unroll
    for (int ct = 0; ct < 4; ++ct)
        #pragma unroll
        for (int nt = 0; nt < 2; ++nt) o[ct][nt] = (f32x4){0.f, 0.f, 0.f, 0.f};
    float mst[2] = {-__builtin_inff(), -__builtin_inff()};
    float lst[2] = {0.f, 0.f};
    const float scale = 0.125f;   // 1/sqrt(64)

    const int ntiles = 2 * qt + 2;
    for (int kt = 0; kt < ntiles; ++kt) {
        const int k0 = kt * 64;
        const int cb = kt & 1;
        __syncthreads();   // drains glds(tile kt); all waves done with buf cb^1

        if (kt + 1 < ntiles) {            // prefetch next tile into other buf
            const int k1 = k0 + 64, nb = cb ^ 1;
            #pragma unroll
            for (int j = 0; j < 2; ++j) {
                const int row = j * 32 + sr8;
                glds16(&qkvb[qkbase + (size_t)(k1 + row) * 3072 + 1024 + h * 64 + sq8 * 8],
                       &KV[nb][0][j * 2048 + ldsw]);
                glds16(&vglob[vbase + (size_t)row * Tt + k1 + sq8 * 8],
                       &KV[nb][1][j * 2048 + ldsw]);
            }
        }

        if (k0 <= q0 + w * 32 + 31) {    // wave-uniform: tile visible
            const u16* Ks = KV[cb][0];
            const u16* Vt = KV[cb][1];

            // S^T = K · Q^T : A = K rows (key-major), B = Q^T (regs)
            bf16x8 ak[4][2];
            #pragma unroll
            for (int mt = 0; mt < 4; ++mt) {
                const int ro = (mt * 16 + m16) * 64;
                ak[mt][0] = *(const bf16x8*)&Ks[ro + slot * 8];
                ak[mt][1] = *(const bf16x8*)&Ks[ro + (slot ^ 4) * 8]; // chunk quad+4
            }
            f32x4 s[4][2];
            #pragma unroll
            for (int mt = 0; mt < 4; ++mt)
                #pragma unroll
                for (int nt = 0; nt < 2; ++nt) {
                    f32x4 a = (f32x4){0.f, 0.f, 0.f, 0.f};
                    a = __builtin_amdgcn_mfma_f32_16x16x32_bf16(ak[mt][0], qb[nt][0], a, 0, 0, 0);
                    a = __builtin_amdgcn_mfma_f32_16x16x32_bf16(ak[mt][1], qb[nt][1], a, 0, 0, 0);
                    s[mt][nt] = a;
                }

            // scale (+ mask only on diagonal-crossing tiles, wave-uniform)
            const int qi0 = q0 + w * 32 + m16;
            if (k0 + 63 > q0 + w * 32) {
                #pragma unroll
                for (int mt = 0; mt < 4; ++mt)
                    #pragma unroll
                    for (int nt = 0; nt < 2; ++nt)
                        #pragma unroll
                        for (int r = 0; r < 4; ++r) {
                            const int key = k0 + mt * 16 + quad * 4 + r;
                            const float v = s[mt][nt][r] * scale;
                            s[mt][nt][r] = (key <= qi0 + nt * 16) ? v : -__builtin_inff();
                        }
            } else {
                #pragma unroll
                for (int mt = 0; mt < 4; ++mt)
                    #pragma unroll
                    for (int nt = 0; nt < 2; ++nt)
                        #pragma unroll
                        for (int r = 0; r < 4; ++r)
                            s[mt][nt][r] *= scale;
            }

            // online softmax: per lane one q per nt; reduce across quads only
            float mx[2] = {-__builtin_inff(), -__builtin_inff()};
            #pragma unroll
            for (int mt = 0; mt < 4; ++mt)
                #pragma unroll
                for (int nt = 0; nt < 2; ++nt)
                    #pragma unroll
                    for (int r = 0; r < 4; ++r)
                        mx[nt] = fmaxf(mx[nt], s[mt][nt][r]);
            #pragma unroll
            for (int nt = 0; nt < 2; ++nt) {
                mx[nt] = fmaxf(mx[nt], __shfl_xor(mx[nt], 16));
                mx[nt] = fmaxf(mx[nt], __shfl_xor(mx[nt], 32));
            }
            float al[2], ls[2];
            #pragma unroll
            for (int nt = 0; nt < 2; ++nt) {
                const float mn = fmaxf(mst[nt], mx[nt]);
                al[nt] = __expf(mst[nt] - mn);   // first tile: exp(-inf)=0
                mst[nt] = mn;
                ls[nt] = 0.f;
            }
            #pragma unroll
            for (int mt = 0; mt < 4; ++mt)
                #pragma unroll
                for (int nt = 0; nt < 2; ++nt) {
                    ushort4 pk;
                    float p0 = __expf(s[mt][nt][0] - mst[nt]);
                    float p1 = __expf(s[mt][nt][1] - mst[nt]);
                    float p2 = __expf(s[mt][nt][2] - mst[nt]);
                    float p3 = __expf(s[mt][nt][3] - mst[nt]);
                    ls[nt] += (p0 + p1) + (p2 + p3);
                    pk.x = f2bf(p0); pk.y = f2bf(p1); pk.z = f2bf(p2); pk.w = f2bf(p3);
                    *(ushort4*)&Pt[(w * 32 + nt * 16 + m16) * 72 + mt * 16 + quad * 4] = pk;
                }
            #pragma unroll
            for (int nt = 0; nt < 2; ++nt) {
                ls[nt] += __shfl_xor(ls[nt], 16);
                ls[nt] += __shfl_xor(ls[nt], 32);
                lst[nt] = lst[nt] * al[nt] + ls[nt];
            }
            #pragma unroll
            for (int ct = 0; ct < 4; ++ct)
                #pragma unroll
                for (int nt = 0; nt < 2; ++nt)
                    #pragma unroll
                    for (int r = 0; r < 4; ++r)
                        o[ct][nt][r] *= al[nt];

            // O^T += V^T · P^T  (same-wave Pt write->read: lgkmcnt only)
            bf16x8 av[4][2], pb[2][2];
            #pragma unroll
            for (int ct = 0; ct < 4; ++ct) {
                const int ro = (ct * 16 + m16) * 64;
                av[ct][0] = *(const bf16x8*)&Vt[ro + slot * 8];
                av[ct][1] = *(const bf16x8*)&Vt[ro + (slot ^ 4) * 8];
            }
            #pragma unroll
            for (int nt = 0; nt < 2; ++nt)
                #pragma unroll
                for (int ks = 0; ks < 2; ++ks)
                    pb[nt][ks] = *(const bf16x8*)&Pt[(w * 32 + nt * 16 + m16) * 72 + ks * 32 + quad * 8];
            #pragma unroll
            for (int ct = 0; ct < 4; ++ct)
                #pragma unroll
                for (int nt = 0; nt < 2; ++nt) {
                    o[ct][nt] = __builtin_amdgcn_mfma_f32_16x16x32_bf16(av[ct][0], pb[nt][0], o[ct][nt], 0, 0, 0);
                    o[ct][nt] = __builtin_amdgcn_mfma_f32_16x16x32_bf16(av[ct][1], pb[nt][1], o[ct][nt], 0, 0, 0);
                }
        }
    }

    // epilogue: O^T -> Ob[q][d] overlay on Pt (own rows only), coalesced store
    float invl[2];
    invl[0] = 1.0f / lst[0];
    invl[1] = 1.0f / lst[1];
    #pragma unroll
    for (int ct = 0; ct < 4; ++ct)
        #pragma unroll
        for (int nt = 0; nt < 2; ++nt) {
            ushort4 pk;   // rows d = 16ct + 4quad + r, col q = 16nt + m16
            pk.x = f2bf(o[ct][nt][0] * invl[nt]);
            pk.y = f2bf(o[ct][nt][1] * invl[nt]);
            pk.z = f2bf(o[ct][nt][2] * invl[nt]);
            pk.w = f2bf(o[ct][nt][3] * invl[nt]);
            *(ushort4*)&Pt[(w * 32 + nt * 16 + m16) * 72 + ct * 16 + quad * 4] = pk;
        }
    __syncthreads();
    // 128 rows x 8 chunks = 1024 int4 chunks -> 4 iterations of 256 threads
    #pragma unroll
    for (int j = 0; j < 4; ++j) {
        const int ci = tid + j * 256;
        const int q = ci >> 3, kc = ci & 7;
        const int4 v = *(const int4*)&Pt[q * 72 + kc * 8];
        *(int4*)&attn_out[(size_t)(b * Tt + q0 + q) * 1024 + h * 64 + kc * 8] = v;
    }
}

// ---------------------------------------------------------------------------
extern "C" void kernel_launch(void* const* d_in, const int* in_sizes, int n_in,
                              void* d_out, int out_size, void* d_ws, size_t ws_size,
                              hipStream_t stream) {
    const float* x    = (const float*)d_in[0];
    const float* Wqkv = (const float*)d_in[1];
    const float* bqkv = (const float*)d_in[2];
    const float* Wout = (const float*)d_in[3];
    const float* bout = (const float*)d_in[4];
    float* out = (float*)d_out;

    u16* xb    = (u16*)d_ws;                                 //  8 MB [4096][1024]
    u16* WqT   = xb    + (size_t)4096 * 1024;                //  6 MB [3072][1024]
    u16* WoT   = WqT   + (size_t)3072 * 1024;                //  2 MB [1024][1024]
    u16* qkvb  = WoT   + (size_t)1024 * 1024;                // 24 MB [4096][3072]
    u16* attb  = qkvb  + (size_t)4096 * 3072;                //  8 MB [4096][1024]
    u16* vglob = attb  + (size_t)4096 * 1024;                //  8 MB [2][16][64][2048]

    cvt_bf16<<<dim3((4096 * 1024) / 8 / 256), dim3(256), 0, stream>>>(x, xb);
    transpose_cvt<<<dim3(3072 / 64, 1024 / 64), dim3(256), 0, stream>>>(Wqkv, WqT, 1024, 3072);
    transpose_cvt<<<dim3(1024 / 64, 1024 / 64), dim3(256), 0, stream>>>(Wout, WoT, 1024, 1024);

    gemm_bt<1><<<dim3(3072 / 128, 4096 / 128), dim3(256), 0, stream>>>(
        xb, WqT, bqkv, qkvb, 4096, 3072, 1024);

    vtrans<<<dim3(Tt / 64, Hh * Bb), dim3(256), 0, stream>>>(qkvb, vglob);

    attn_mfma<<<dim3(Hh * Bb, Tt / 128), dim3(256), 0, stream>>>(qkvb, vglob, attb);

    gemm_bt<0><<<dim3(1024 / 128, 4096 / 128), dim3(256), 0, stream>>>(
        attb, WoT, bout, out, 4096, 1024, 1024);
}

// Round 8
// 198.128 us; speedup vs baseline: 10.6759x; 1.1037x over previous
//
#include <hip/hip_runtime.h>
#include <hip/hip_bf16.h>
#include <hip/hip_fp16.h>

typedef __attribute__((ext_vector_type(8))) short bf16x8;   // 8 bf16 = 4 VGPRs
typedef __attribute__((ext_vector_type(4))) float f32x4;
typedef unsigned short u16;
typedef unsigned int uint;

#define Bb 2
#define Tt 2048
#define Dd 1024
#define Hh 16

#define EXP2F(x) __builtin_amdgcn_exp2f(x)

__device__ inline u16 f2bf(float f) {
    union { float f; uint u; } v; v.f = f;
    uint r = v.u + 0x7fffu + ((v.u >> 16) & 1u);   // RNE
    return (u16)(r >> 16);
}
__device__ inline uint fbits(float f) { union { float f; uint u; } v; v.f = f; return v.u; }
__device__ inline u16 f2h(float f) { return __half_as_ushort(__float2half(f)); }
__device__ inline float h2f(u16 u) { return __half2float(__ushort_as_half(u)); }

// async global->LDS, 16B per lane; dest wave-uniform base + lane*16.
__device__ inline void glds16(const u16* g, u16* l) {
    __builtin_amdgcn_global_load_lds(
        (const __attribute__((address_space(1))) void*)g,
        (__attribute__((address_space(3))) void*)l,
        16, 0, 0);
}

// ---------------------------------------------------------------------------
// fp32 -> bf16 elementwise (8 elems/thread)
// ---------------------------------------------------------------------------
__global__ __launch_bounds__(256) void cvt_bf16(
    const float* __restrict__ in, u16* __restrict__ out)
{
    const size_t i = ((size_t)blockIdx.x * 256 + threadIdx.x) * 8;
    const float4 a = *(const float4*)&in[i];
    const float4 b = *(const float4*)&in[i + 4];
    uint4 o;
    o.x = (uint)f2bf(a.x) | ((uint)f2bf(a.y) << 16);
    o.y = (uint)f2bf(a.z) | ((uint)f2bf(a.w) << 16);
    o.z = (uint)f2bf(b.x) | ((uint)f2bf(b.y) << 16);
    o.w = (uint)f2bf(b.z) | ((uint)f2bf(b.w) << 16);
    *(uint4*)&out[i] = o;
}

// ---------------------------------------------------------------------------
// W[K][N] fp32 -> Wt[N][K] bf16, 64x64 LDS tile
// ---------------------------------------------------------------------------
__global__ __launch_bounds__(256) void transpose_cvt(
    const float* __restrict__ W, u16* __restrict__ Wt, int K, int N)
{
    __shared__ float tile[64][65];
    const int k0 = blockIdx.y * 64, n0 = blockIdx.x * 64;
    const int tid = threadIdx.x;
    const int tr = tid >> 4;
    const int tc = (tid & 15) * 4;

    #pragma unroll
    for (int i = 0; i < 4; ++i) {
        const float4 v = *(const float4*)&W[(size_t)(k0 + tr + i * 16) * N + n0 + tc];
        tile[tr + i * 16][tc + 0] = v.x;
        tile[tr + i * 16][tc + 1] = v.y;
        tile[tr + i * 16][tc + 2] = v.z;
        tile[tr + i * 16][tc + 3] = v.w;
    }
    __syncthreads();
    #pragma unroll
    for (int i = 0; i < 4; ++i) {
        ushort4 o;
        o.x = f2bf(tile[tc + 0][tr + i * 16]);
        o.y = f2bf(tile[tc + 1][tr + i * 16]);
        o.z = f2bf(tile[tc + 2][tr + i * 16]);
        o.w = f2bf(tile[tc + 3][tr + i * 16]);
        *(ushort4*)&Wt[(size_t)(n0 + tr + i * 16) * K + k0 + tc] = o;
    }
}

// ---------------------------------------------------------------------------
// C = A @ Bt^T + bias, bf16 MFMA, m97 pattern (glds w=16, XOR swizzle).
// MODE 0: fp32 out, row-major stride N (gemm2).
// MODE 1: qkv proj: cols <2048 -> bf16 qkvb stride 2048 (Q,K);
//         cols >=2048 -> V scattered transposed into vg[b][h][d][T].
// ---------------------------------------------------------------------------
template <int MODE>
__global__ __launch_bounds__(256) void gemm_bt(
    const u16* __restrict__ A, const u16* __restrict__ Bt,
    const float* __restrict__ bias, void* __restrict__ C,
    u16* __restrict__ vg, int M, int N, int K)
{
    __shared__ u16 As[128 * 32];
    __shared__ u16 Bs[128 * 32];

    const int tid  = threadIdx.x;
    const int lane = tid & 63;
    const int w    = tid >> 6;
    const int wm   = w >> 1, wn = w & 1;
    const int quad = lane >> 4;
    const int m16  = lane & 15;
    const int row0 = blockIdx.y * 128;
    const int col0 = blockIdx.x * 128;

    f32x4 acc[4][4];
    #pragma unroll
    for (int i = 0; i < 4; ++i)
        #pragma unroll
        for (int j = 0; j < 4; ++j) acc[i][j] = (f32x4){0.f, 0.f, 0.f, 0.f};

    const int sr  = tid >> 2, sqs = tid & 3;
    const int sq  = sqs ^ ((sr >> 1) & 3);
    const int ldsw = w * 512;
    const int slot = quad ^ ((m16 >> 1) & 3);

    for (int ko = 0; ko < K; ko += 32) {
        __syncthreads();
        glds16(&A [(size_t)(row0 + sr) * K + ko + sq * 8],       &As[ldsw]);
        glds16(&A [(size_t)(row0 + sr + 64) * K + ko + sq * 8],  &As[2048 + ldsw]);
        glds16(&Bt[(size_t)(col0 + sr) * K + ko + sq * 8],       &Bs[ldsw]);
        glds16(&Bt[(size_t)(col0 + sr + 64) * K + ko + sq * 8],  &Bs[2048 + ldsw]);
        __syncthreads();

        bf16x8 af[4], bfr[4];
        #pragma unroll
        for (int mt = 0; mt < 4; ++mt)
            af[mt] = *(const bf16x8*)&As[(wm * 64 + mt * 16 + m16) * 32 + slot * 8];
        #pragma unroll
        for (int nt = 0; nt < 4; ++nt)
            bfr[nt] = *(const bf16x8*)&Bs[(wn * 64 + nt * 16 + m16) * 32 + slot * 8];
        #pragma unroll
        for (int mt = 0; mt < 4; ++mt)
            #pragma unroll
            for (int nt = 0; nt < 4; ++nt)
                acc[mt][nt] = __builtin_amdgcn_mfma_f32_16x16x32_bf16(
                    af[mt], bfr[nt], acc[mt][nt], 0, 0, 0);
    }

    #pragma unroll
    for (int mt = 0; mt < 4; ++mt) {
        #pragma unroll
        for (int nt = 0; nt < 4; ++nt) {
            const int row = row0 + wm * 64 + mt * 16 + quad * 4;
            const int col = col0 + wn * 64 + nt * 16 + m16;
            const float bv = bias[col];
            #pragma unroll
            for (int r = 0; r < 4; ++r) {
                const float v = acc[mt][nt][r] + bv;
                if (MODE == 0) {
                    ((float*)C)[(size_t)(row + r) * N + col] = v;
                } else {
                    if (col0 < 2048) {   // Q,K region (block never straddles)
                        ((u16*)C)[(size_t)(row + r) * 2048 + col] = f2bf(v);
                    } else {             // V: write transposed into vg[b][h][d][T]
                        const int hcol = col - 2048;
                        const int hh = hcol >> 6, dd = hcol & 63;
                        const int bb = (row + r) >> 11, tt = (row + r) & 2047;
                        vg[((size_t)(bb * Hh + hh) * 64 + dd) * Tt + tt] = f2bf(v);
                    }
                }
            }
        }
    }
}

// ---------------------------------------------------------------------------
// Flash causal attention v6: split-K(2) + fixed-offset softmax.
// qkvb [B*T][2048] = Q(0..1023) K(1024..2047), head-major; vglob [b][h][d][T].
// Grid (32 hb, 32 y): qt = 15 - (y>>1), half = y&1; tiles kt = half, half+2,..
// 4 waves x 32 q-rows; single-buffer KV (16 KB) + Pt (18 KB) = 34 KB
// -> 4 blocks/CU = 16 waves/CU.
// p = exp2(s*sc2 - 8)  (no running max: additive partials; l deferred).
// Partials: wsO fp16 [2][4096][1024], wsL fp32 [2][16][4096].
// ---------------------------------------------------------------------------
__global__ __launch_bounds__(256, 4) void attn_split(
    const u16* __restrict__ qkvb, const u16* __restrict__ vglob,
    u16* __restrict__ wsO, float* __restrict__ wsL)
{
    const int hb  = blockIdx.x;
    const int h   = hb & 15, b = hb >> 4;
    const int qt  = 15 - (blockIdx.y >> 1);   // heavy-first
    const int half = blockIdx.y & 1;
    const int tid = threadIdx.x;
    const int lane = tid & 63, w = tid >> 6;
    const int quad = lane >> 4, m16 = lane & 15;

    __shared__ u16 KV[2][64 * 64];       // [0]=K, [1]=Vt, 16 KB
    __shared__ u16 Pt[128 * 72];         // 18 KB

    const int q0 = qt * 128;
    const size_t qkbase = (size_t)(b * Tt) * 2048;
    const size_t vbase  = (size_t)((b * Hh + h) * 64) * Tt;

    const int sr8 = tid >> 3;                // 0..31
    const int sq8 = (tid & 7) ^ (sr8 & 7);
    const int ldsw = w * 512;
    const int slot = quad ^ (m16 & 7);       // ks=0 read slot; ks=1 -> ^4

    // Q^T B-frags, loop-invariant, from global:
    bf16x8 qb[2][2];
    #pragma unroll
    for (int nt = 0; nt < 2; ++nt)
        #pragma unroll
        for (int ks = 0; ks < 2; ++ks)
            qb[nt][ks] = *(const bf16x8*)&qkvb[
                qkbase + (size_t)(q0 + w * 32 + nt * 16 + m16) * 2048
                + h * 64 + ks * 32 + quad * 8];

    f32x4 o[4][2];
    #pragma unroll
    for (int ct = 0; ct < 4; ++ct)
        #pragma unroll
        for (int nt = 0; nt < 2; ++nt) o[ct][nt] = (f32x4){0.f, 0.f, 0.f, 0.f};
    float ls[2] = {0.f, 0.f};
    const float sc2 = 0.125f * 1.4426950408889634f;   // scale*log2(e)

    const int ntiles = 2 * qt + 2;
    for (int kt = half; kt < ntiles; kt += 2) {
        const int k0 = kt * 64;
        __syncthreads();   // all waves done with previous KV
        #pragma unroll
        for (int j = 0; j < 2; ++j) {
            const int row = j * 32 + sr8;
            glds16(&qkvb[qkbase + (size_t)(k0 + row) * 2048 + 1024 + h * 64 + sq8 * 8],
                   &KV[0][j * 2048 + ldsw]);
            glds16(&vglob[vbase + (size_t)row * Tt + k0 + sq8 * 8],
                   &KV[1][j * 2048 + ldsw]);
        }
        __syncthreads();   // vmcnt drain -> tiles visible

        if (k0 <= q0 + w * 32 + 31) {    // wave-uniform visibility
            const u16* Ks = KV[0];
            const u16* Vt = KV[1];

            // S^T = K · Q^T
            bf16x8 ak[4][2];
            #pragma unroll
            for (int mt = 0; mt < 4; ++mt) {
                const int ro = (mt * 16 + m16) * 64;
                ak[mt][0] = *(const bf16x8*)&Ks[ro + slot * 8];
                ak[mt][1] = *(const bf16x8*)&Ks[ro + (slot ^ 4) * 8];
            }
            f32x4 s[4][2];
            #pragma unroll
            for (int mt = 0; mt < 4; ++mt)
                #pragma unroll
                for (int nt = 0; nt < 2; ++nt) {
                    f32x4 a = (f32x4){0.f, 0.f, 0.f, 0.f};
                    a = __builtin_amdgcn_mfma_f32_16x16x32_bf16(ak[mt][0], qb[nt][0], a, 0, 0, 0);
                    a = __builtin_amdgcn_mfma_f32_16x16x32_bf16(ak[mt][1], qb[nt][1], a, 0, 0, 0);
                    s[mt][nt] = a;
                }

            // p = exp2(s*sc2 - 8), causal mask -> 0; accumulate l per-lane.
            const int qi0 = q0 + w * 32 + m16;
            const bool diag = (k0 + 63 > q0 + w * 32);
            #pragma unroll
            for (int mt = 0; mt < 4; ++mt)
                #pragma unroll
                for (int nt = 0; nt < 2; ++nt) {
                    float p[4];
                    const int kb = k0 + mt * 16 + quad * 4;
                    #pragma unroll
                    for (int r = 0; r < 4; ++r) {
                        float t = __builtin_fmaf(s[mt][nt][r], sc2, -8.0f);
                        if (diag) t = (kb + r <= qi0 + nt * 16) ? t : -1000.0f;
                        p[r] = EXP2F(t);
                    }
                    ls[nt] += (p[0] + p[1]) + (p[2] + p[3]);
                    uint2 pk;   // truncation-pack to bf16 pairs
                    pk.x = (fbits(p[0]) >> 16) | (fbits(p[1]) & 0xffff0000u);
                    pk.y = (fbits(p[2]) >> 16) | (fbits(p[3]) & 0xffff0000u);
                    *(uint2*)&Pt[(w * 32 + nt * 16 + m16) * 72 + mt * 16 + quad * 4] = pk;
                }

            // O^T += V^T · P^T  (same-wave Pt write->read)
            bf16x8 av[4][2], pb[2][2];
            #pragma unroll
            for (int ct = 0; ct < 4; ++ct) {
                const int ro = (ct * 16 + m16) * 64;
                av[ct][0] = *(const bf16x8*)&Vt[ro + slot * 8];
                av[ct][1] = *(const bf16x8*)&Vt[ro + (slot ^ 4) * 8];
            }
            #pragma unroll
            for (int nt = 0; nt < 2; ++nt)
                #pragma unroll
                for (int ks = 0; ks < 2; ++ks)
                    pb[nt][ks] = *(const bf16x8*)&Pt[(w * 32 + nt * 16 + m16) * 72 + ks * 32 + quad * 8];
            #pragma unroll
            for (int ct = 0; ct < 4; ++ct)
                #pragma unroll
                for (int nt = 0; nt < 2; ++nt) {
                    o[ct][nt] = __builtin_amdgcn_mfma_f32_16x16x32_bf16(av[ct][0], pb[nt][0], o[ct][nt], 0, 0, 0);
                    o[ct][nt] = __builtin_amdgcn_mfma_f32_16x16x32_bf16(av[ct][1], pb[nt][1], o[ct][nt], 0, 0, 0);
                }
        }
    }

    // epilogue: deferred l reduce (once), store fp16 O partial + fp32 l.
    #pragma unroll
    for (int nt = 0; nt < 2; ++nt) {
        ls[nt] += __shfl_xor(ls[nt], 16);
        ls[nt] += __shfl_xor(ls[nt], 32);
    }
    const int qrow = b * Tt + q0 + w * 32 + m16;
    if (quad == 0) {
        wsL[(half * Hh + h) * 4096 + qrow]      = ls[0];
        wsL[(half * Hh + h) * 4096 + qrow + 16] = ls[1];
    }
    #pragma unroll
    for (int ct = 0; ct < 4; ++ct)
        #pragma unroll
        for (int nt = 0; nt < 2; ++nt) {
            ushort4 pk;
            pk.x = f2h(o[ct][nt][0]);
            pk.y = f2h(o[ct][nt][1]);
            pk.z = f2h(o[ct][nt][2]);
            pk.w = f2h(o[ct][nt][3]);
            *(ushort4*)&wsO[((size_t)(half * 4096 + qrow + nt * 16)) * 1024
                            + h * 64 + ct * 16 + quad * 4] = pk;
        }
}

// ---------------------------------------------------------------------------
// combine: attb = bf16( (O0+O1) / (l0+l1) ), 8 elems/thread.
// ---------------------------------------------------------------------------
__global__ __launch_bounds__(256) void combine(
    const u16* __restrict__ wsO, const float* __restrict__ wsL,
    u16* __restrict__ attb)
{
    const int gi  = (blockIdx.x * 256 + threadIdx.x) * 8;
    const int row = gi >> 10;
    const int h   = (gi & 1023) >> 6;
    const float il = 1.0f / (wsL[h * 4096 + row] + wsL[(Hh + h) * 4096 + row]);
    const uint4 a = *(const uint4*)&wsO[gi];
    const uint4 c = *(const uint4*)&wsO[(size_t)4096 * 1024 + gi];
    const uint aw[4] = {a.x, a.y, a.z, a.w};
    const uint cw[4] = {c.x, c.y, c.z, c.w};
    uint ow[4];
    #pragma unroll
    for (int i = 0; i < 4; ++i) {
        const float r0 = (h2f((u16)(aw[i] & 0xffff)) + h2f((u16)(cw[i] & 0xffff))) * il;
        const float r1 = (h2f((u16)(aw[i] >> 16))    + h2f((u16)(cw[i] >> 16)))    * il;
        ow[i] = (uint)f2bf(r0) | ((uint)f2bf(r1) << 16);
    }
    uint4 o4; o4.x = ow[0]; o4.y = ow[1]; o4.z = ow[2]; o4.w = ow[3];
    *(uint4*)&attb[gi] = o4;
}

// ---------------------------------------------------------------------------
extern "C" void kernel_launch(void* const* d_in, const int* in_sizes, int n_in,
                              void* d_out, int out_size, void* d_ws, size_t ws_size,
                              hipStream_t stream) {
    const float* x    = (const float*)d_in[0];
    const float* Wqkv = (const float*)d_in[1];
    const float* bqkv = (const float*)d_in[2];
    const float* Wout = (const float*)d_in[3];
    const float* bout = (const float*)d_in[4];
    float* out = (float*)d_out;

    u16*   xb    = (u16*)d_ws;                               //  8 MB [4096][1024]
    u16*   WqT   = xb    + (size_t)4096 * 1024;              //  6 MB [3072][1024]
    u16*   WoT   = WqT   + (size_t)3072 * 1024;              //  2 MB [1024][1024]
    u16*   qkvb  = WoT   + (size_t)1024 * 1024;              // 16 MB [4096][2048] Q,K
    u16*   attb  = qkvb  + (size_t)4096 * 2048;              //  8 MB [4096][1024]
    u16*   vglob = attb  + (size_t)4096 * 1024;              //  8 MB [2][16][64][2048]
    u16*   wsO   = vglob + (size_t)4096 * 2048;              // 16 MB [2][4096][1024] fp16
    float* wsL   = (float*)(wsO + (size_t)2 * 4096 * 1024);  // 512 KB [2][16][4096]

    cvt_bf16<<<dim3((4096 * 1024) / 8 / 256), dim3(256), 0, stream>>>(x, xb);
    transpose_cvt<<<dim3(3072 / 64, 1024 / 64), dim3(256), 0, stream>>>(Wqkv, WqT, 1024, 3072);
    transpose_cvt<<<dim3(1024 / 64, 1024 / 64), dim3(256), 0, stream>>>(Wout, WoT, 1024, 1024);

    gemm_bt<1><<<dim3(3072 / 128, 4096 / 128), dim3(256), 0, stream>>>(
        xb, WqT, bqkv, qkvb, vglob, 4096, 3072, 1024);

    attn_split<<<dim3(Hh * Bb, 32), dim3(256), 0, stream>>>(qkvb, vglob, wsO, wsL);

    combine<<<dim3((4096 * 1024) / 8 / 256), dim3(256), 0, stream>>>(wsO, wsL, attb);

    gemm_bt<0><<<dim3(1024 / 128, 4096 / 128), dim3(256), 0, stream>>>(
        attb, WoT, bout, out, nullptr, 4096, 1024, 1024);
}

// Round 9
// 188.467 us; speedup vs baseline: 11.2231x; 1.0513x over previous
//
#include <hip/hip_runtime.h>
#include <hip/hip_bf16.h>
#include <hip/hip_fp16.h>

typedef __attribute__((ext_vector_type(8))) short bf16x8;   // 8 bf16 = 4 VGPRs
typedef __attribute__((ext_vector_type(4))) float f32x4;
typedef unsigned short u16;
typedef unsigned int uint;

#define Bb 2
#define Tt 2048
#define Dd 1024
#define Hh 16

#define EXP2F(x) __builtin_amdgcn_exp2f(x)

__device__ inline u16 f2bf(float f) {
    union { float f; uint u; } v; v.f = f;
    uint r = v.u + 0x7fffu + ((v.u >> 16) & 1u);   // RNE
    return (u16)(r >> 16);
}
__device__ inline uint fbits(float f) { union { float f; uint u; } v; v.f = f; return v.u; }
__device__ inline u16 f2h(float f) { return __half_as_ushort(__float2half(f)); }
__device__ inline float h2f(u16 u) { return __half2float(__ushort_as_half(u)); }

// async global->LDS, 16B per lane; dest wave-uniform base + lane*16.
__device__ inline void glds16(const u16* g, u16* l) {
    __builtin_amdgcn_global_load_lds(
        (const __attribute__((address_space(1))) void*)g,
        (__attribute__((address_space(3))) void*)l,
        16, 0, 0);
}

// ---------------------------------------------------------------------------
// fp32 -> bf16 elementwise (8 elems/thread)
// ---------------------------------------------------------------------------
__global__ __launch_bounds__(256) void cvt_bf16(
    const float* __restrict__ in, u16* __restrict__ out)
{
    const size_t i = ((size_t)blockIdx.x * 256 + threadIdx.x) * 8;
    const float4 a = *(const float4*)&in[i];
    const float4 b = *(const float4*)&in[i + 4];
    uint4 o;
    o.x = (uint)f2bf(a.x) | ((uint)f2bf(a.y) << 16);
    o.y = (uint)f2bf(a.z) | ((uint)f2bf(a.w) << 16);
    o.z = (uint)f2bf(b.x) | ((uint)f2bf(b.y) << 16);
    o.w = (uint)f2bf(b.z) | ((uint)f2bf(b.w) << 16);
    *(uint4*)&out[i] = o;
}

// ---------------------------------------------------------------------------
// W[K][N] fp32 -> Wt[N][K] bf16, 64x64 LDS tile
// ---------------------------------------------------------------------------
__global__ __launch_bounds__(256) void transpose_cvt(
    const float* __restrict__ W, u16* __restrict__ Wt, int K, int N)
{
    __shared__ float tile[64][65];
    const int k0 = blockIdx.y * 64, n0 = blockIdx.x * 64;
    const int tid = threadIdx.x;
    const int tr = tid >> 4;
    const int tc = (tid & 15) * 4;

    #pragma unroll
    for (int i = 0; i < 4; ++i) {
        const float4 v = *(const float4*)&W[(size_t)(k0 + tr + i * 16) * N + n0 + tc];
        tile[tr + i * 16][tc + 0] = v.x;
        tile[tr + i * 16][tc + 1] = v.y;
        tile[tr + i * 16][tc + 2] = v.z;
        tile[tr + i * 16][tc + 3] = v.w;
    }
    __syncthreads();
    #pragma unroll
    for (int i = 0; i < 4; ++i) {
        ushort4 o;
        o.x = f2bf(tile[tc + 0][tr + i * 16]);
        o.y = f2bf(tile[tc + 1][tr + i * 16]);
        o.z = f2bf(tile[tc + 2][tr + i * 16]);
        o.w = f2bf(tile[tc + 3][tr + i * 16]);
        *(ushort4*)&Wt[(size_t)(n0 + tr + i * 16) * K + k0 + tc] = o;
    }
}

// ---------------------------------------------------------------------------
// C = A @ Bt^T + bias, bf16 MFMA. m97-style glds staging + double-buffered
// prefetch (one barrier per K-iter; glds for iter k+1 issued right after the
// barrier that publishes iter k, drains at the next barrier after a full
// compute phase). 2x16 KB LDS. XOR source swizzle, conflict-free frag reads.
// MODE 0: fp32 out, row-major stride N (gemm2).
// MODE 1: qkv proj: cols <2048 -> bf16 qkvb stride 2048 (Q,K);
//         cols >=2048 -> V scattered transposed into vg[b][h][d][T].
// ---------------------------------------------------------------------------
template <int MODE>
__global__ __launch_bounds__(256) void gemm_bt(
    const u16* __restrict__ A, const u16* __restrict__ Bt,
    const float* __restrict__ bias, void* __restrict__ C,
    u16* __restrict__ vg, int M, int N, int K)
{
    __shared__ u16 As[2][128 * 32];
    __shared__ u16 Bs[2][128 * 32];

    const int tid  = threadIdx.x;
    const int lane = tid & 63;
    const int w    = tid >> 6;
    const int wm   = w >> 1, wn = w & 1;
    const int quad = lane >> 4;
    const int m16  = lane & 15;
    const int row0 = blockIdx.y * 128;
    const int col0 = blockIdx.x * 128;

    f32x4 acc[4][4];
    #pragma unroll
    for (int i = 0; i < 4; ++i)
        #pragma unroll
        for (int j = 0; j < 4; ++j) acc[i][j] = (f32x4){0.f, 0.f, 0.f, 0.f};

    const int sr  = tid >> 2, sqs = tid & 3;
    const int sq  = sqs ^ ((sr >> 1) & 3);
    const int ldsw = w * 512;
    const int slot = quad ^ ((m16 >> 1) & 3);

    const int nIter = K >> 5;

    // prologue: stage iter 0 into buf 0
    glds16(&A [(size_t)(row0 + sr) * K + sq * 8],       &As[0][ldsw]);
    glds16(&A [(size_t)(row0 + sr + 64) * K + sq * 8],  &As[0][2048 + ldsw]);
    glds16(&Bt[(size_t)(col0 + sr) * K + sq * 8],       &Bs[0][ldsw]);
    glds16(&Bt[(size_t)(col0 + sr + 64) * K + sq * 8],  &Bs[0][2048 + ldsw]);

    for (int it = 0; it < nIter; ++it) {
        const int cb = it & 1;
        __syncthreads();   // drains glds(iter it); all waves done reading buf cb^1

        if (it + 1 < nIter) {   // prefetch next k-slab into the other buffer
            const int ko = (it + 1) << 5;
            const int nb = cb ^ 1;
            glds16(&A [(size_t)(row0 + sr) * K + ko + sq * 8],       &As[nb][ldsw]);
            glds16(&A [(size_t)(row0 + sr + 64) * K + ko + sq * 8],  &As[nb][2048 + ldsw]);
            glds16(&Bt[(size_t)(col0 + sr) * K + ko + sq * 8],       &Bs[nb][ldsw]);
            glds16(&Bt[(size_t)(col0 + sr + 64) * K + ko + sq * 8],  &Bs[nb][2048 + ldsw]);
        }

        bf16x8 af[4], bfr[4];
        #pragma unroll
        for (int mt = 0; mt < 4; ++mt)
            af[mt] = *(const bf16x8*)&As[cb][(wm * 64 + mt * 16 + m16) * 32 + slot * 8];
        #pragma unroll
        for (int nt = 0; nt < 4; ++nt)
            bfr[nt] = *(const bf16x8*)&Bs[cb][(wn * 64 + nt * 16 + m16) * 32 + slot * 8];
        #pragma unroll
        for (int mt = 0; mt < 4; ++mt)
            #pragma unroll
            for (int nt = 0; nt < 4; ++nt)
                acc[mt][nt] = __builtin_amdgcn_mfma_f32_16x16x32_bf16(
                    af[mt], bfr[nt], acc[mt][nt], 0, 0, 0);
    }

    #pragma unroll
    for (int mt = 0; mt < 4; ++mt) {
        #pragma unroll
        for (int nt = 0; nt < 4; ++nt) {
            const int row = row0 + wm * 64 + mt * 16 + quad * 4;
            const int col = col0 + wn * 64 + nt * 16 + m16;
            const float bv = bias[col];
            #pragma unroll
            for (int r = 0; r < 4; ++r) {
                const float v = acc[mt][nt][r] + bv;
                if (MODE == 0) {
                    ((float*)C)[(size_t)(row + r) * N + col] = v;
                } else {
                    if (col0 < 2048) {   // Q,K region (block never straddles)
                        ((u16*)C)[(size_t)(row + r) * 2048 + col] = f2bf(v);
                    } else {             // V: write transposed into vg[b][h][d][T]
                        const int hcol = col - 2048;
                        const int hh = hcol >> 6, dd = hcol & 63;
                        const int bb = (row + r) >> 11, tt = (row + r) & 2047;
                        vg[((size_t)(bb * Hh + hh) * 64 + dd) * Tt + tt] = f2bf(v);
                    }
                }
            }
        }
    }
}

// ---------------------------------------------------------------------------
// Flash causal attention v6: split-K(2) + fixed-offset softmax. (unchanged R8)
// ---------------------------------------------------------------------------
__global__ __launch_bounds__(256, 4) void attn_split(
    const u16* __restrict__ qkvb, const u16* __restrict__ vglob,
    u16* __restrict__ wsO, float* __restrict__ wsL)
{
    const int hb  = blockIdx.x;
    const int h   = hb & 15, b = hb >> 4;
    const int qt  = 15 - (blockIdx.y >> 1);   // heavy-first
    const int half = blockIdx.y & 1;
    const int tid = threadIdx.x;
    const int lane = tid & 63, w = tid >> 6;
    const int quad = lane >> 4, m16 = lane & 15;

    __shared__ u16 KV[2][64 * 64];       // [0]=K, [1]=Vt, 16 KB
    __shared__ u16 Pt[128 * 72];         // 18 KB

    const int q0 = qt * 128;
    const size_t qkbase = (size_t)(b * Tt) * 2048;
    const size_t vbase  = (size_t)((b * Hh + h) * 64) * Tt;

    const int sr8 = tid >> 3;                // 0..31
    const int sq8 = (tid & 7) ^ (sr8 & 7);
    const int ldsw = w * 512;
    const int slot = quad ^ (m16 & 7);       // ks=0 read slot; ks=1 -> ^4

    // Q^T B-frags, loop-invariant, from global:
    bf16x8 qb[2][2];
    #pragma unroll
    for (int nt = 0; nt < 2; ++nt)
        #pragma unroll
        for (int ks = 0; ks < 2; ++ks)
            qb[nt][ks] = *(const bf16x8*)&qkvb[
                qkbase + (size_t)(q0 + w * 32 + nt * 16 + m16) * 2048
                + h * 64 + ks * 32 + quad * 8];

    f32x4 o[4][2];
    #pragma unroll
    for (int ct = 0; ct < 4; ++ct)
        #pragma unroll
        for (int nt = 0; nt < 2; ++nt) o[ct][nt] = (f32x4){0.f, 0.f, 0.f, 0.f};
    float ls[2] = {0.f, 0.f};
    const float sc2 = 0.125f * 1.4426950408889634f;   // scale*log2(e)

    const int ntiles = 2 * qt + 2;
    for (int kt = half; kt < ntiles; kt += 2) {
        const int k0 = kt * 64;
        __syncthreads();   // all waves done with previous KV
        #pragma unroll
        for (int j = 0; j < 2; ++j) {
            const int row = j * 32 + sr8;
            glds16(&qkvb[qkbase + (size_t)(k0 + row) * 2048 + 1024 + h * 64 + sq8 * 8],
                   &KV[0][j * 2048 + ldsw]);
            glds16(&vglob[vbase + (size_t)row * Tt + k0 + sq8 * 8],
                   &KV[1][j * 2048 + ldsw]);
        }
        __syncthreads();   // vmcnt drain -> tiles visible

        if (k0 <= q0 + w * 32 + 31) {    // wave-uniform visibility
            const u16* Ks = KV[0];
            const u16* Vt = KV[1];

            // S^T = K · Q^T
            bf16x8 ak[4][2];
            #pragma unroll
            for (int mt = 0; mt < 4; ++mt) {
                const int ro = (mt * 16 + m16) * 64;
                ak[mt][0] = *(const bf16x8*)&Ks[ro + slot * 8];
                ak[mt][1] = *(const bf16x8*)&Ks[ro + (slot ^ 4) * 8];
            }
            f32x4 s[4][2];
            #pragma unroll
            for (int mt = 0; mt < 4; ++mt)
                #pragma unroll
                for (int nt = 0; nt < 2; ++nt) {
                    f32x4 a = (f32x4){0.f, 0.f, 0.f, 0.f};
                    a = __builtin_amdgcn_mfma_f32_16x16x32_bf16(ak[mt][0], qb[nt][0], a, 0, 0, 0);
                    a = __builtin_amdgcn_mfma_f32_16x16x32_bf16(ak[mt][1], qb[nt][1], a, 0, 0, 0);
                    s[mt][nt] = a;
                }

            // p = exp2(s*sc2 - 8), causal mask -> 0; accumulate l per-lane.
            const int qi0 = q0 + w * 32 + m16;
            const bool diag = (k0 + 63 > q0 + w * 32);
            #pragma unroll
            for (int mt = 0; mt < 4; ++mt)
                #pragma unroll
                for (int nt = 0; nt < 2; ++nt) {
                    float p[4];
                    const int kb = k0 + mt * 16 + quad * 4;
                    #pragma unroll
                    for (int r = 0; r < 4; ++r) {
                        float t = __builtin_fmaf(s[mt][nt][r], sc2, -8.0f);
                        if (diag) t = (kb + r <= qi0 + nt * 16) ? t : -1000.0f;
                        p[r] = EXP2F(t);
                    }
                    ls[nt] += (p[0] + p[1]) + (p[2] + p[3]);
                    uint2 pk;   // truncation-pack to bf16 pairs
                    pk.x = (fbits(p[0]) >> 16) | (fbits(p[1]) & 0xffff0000u);
                    pk.y = (fbits(p[2]) >> 16) | (fbits(p[3]) & 0xffff0000u);
                    *(uint2*)&Pt[(w * 32 + nt * 16 + m16) * 72 + mt * 16 + quad * 4] = pk;
                }

            // O^T += V^T · P^T  (same-wave Pt write->read)
            bf16x8 av[4][2], pb[2][2];
            #pragma unroll
            for (int ct = 0; ct < 4; ++ct) {
                const int ro = (ct * 16 + m16) * 64;
                av[ct][0] = *(const bf16x8*)&Vt[ro + slot * 8];
                av[ct][1] = *(const bf16x8*)&Vt[ro + (slot ^ 4) * 8];
            }
            #pragma unroll
            for (int nt = 0; nt < 2; ++nt)
                #pragma unroll
                for (int ks = 0; ks < 2; ++ks)
                    pb[nt][ks] = *(const bf16x8*)&Pt[(w * 32 + nt * 16 + m16) * 72 + ks * 32 + quad * 8];
            #pragma unroll
            for (int ct = 0; ct < 4; ++ct)
                #pragma unroll
                for (int nt = 0; nt < 2; ++nt) {
                    o[ct][nt] = __builtin_amdgcn_mfma_f32_16x16x32_bf16(av[ct][0], pb[nt][0], o[ct][nt], 0, 0, 0);
                    o[ct][nt] = __builtin_amdgcn_mfma_f32_16x16x32_bf16(av[ct][1], pb[nt][1], o[ct][nt], 0, 0, 0);
                }
        }
    }

    // epilogue: deferred l reduce (once), store fp16 O partial + fp32 l.
    #pragma unroll
    for (int nt = 0; nt < 2; ++nt) {
        ls[nt] += __shfl_xor(ls[nt], 16);
        ls[nt] += __shfl_xor(ls[nt], 32);
    }
    const int qrow = b * Tt + q0 + w * 32 + m16;
    if (quad == 0) {
        wsL[(half * Hh + h) * 4096 + qrow]      = ls[0];
        wsL[(half * Hh + h) * 4096 + qrow + 16] = ls[1];
    }
    #pragma unroll
    for (int ct = 0; ct < 4; ++ct)
        #pragma unroll
        for (int nt = 0; nt < 2; ++nt) {
            ushort4 pk;
            pk.x = f2h(o[ct][nt][0]);
            pk.y = f2h(o[ct][nt][1]);
            pk.z = f2h(o[ct][nt][2]);
            pk.w = f2h(o[ct][nt][3]);
            *(ushort4*)&wsO[((size_t)(half * 4096 + qrow + nt * 16)) * 1024
                            + h * 64 + ct * 16 + quad * 4] = pk;
        }
}

// ---------------------------------------------------------------------------
// combine: attb = bf16( (O0+O1) / (l0+l1) ), 8 elems/thread.
// ---------------------------------------------------------------------------
__global__ __launch_bounds__(256) void combine(
    const u16* __restrict__ wsO, const float* __restrict__ wsL,
    u16* __restrict__ attb)
{
    const int gi  = (blockIdx.x * 256 + threadIdx.x) * 8;
    const int row = gi >> 10;
    const int h   = (gi & 1023) >> 6;
    const float il = 1.0f / (wsL[h * 4096 + row] + wsL[(Hh + h) * 4096 + row]);
    const uint4 a = *(const uint4*)&wsO[gi];
    const uint4 c = *(const uint4*)&wsO[(size_t)4096 * 1024 + gi];
    const uint aw[4] = {a.x, a.y, a.z, a.w};
    const uint cw[4] = {c.x, c.y, c.z, c.w};
    uint ow[4];
    #pragma unroll
    for (int i = 0; i < 4; ++i) {
        const float r0 = (h2f((u16)(aw[i] & 0xffff)) + h2f((u16)(cw[i] & 0xffff))) * il;
        const float r1 = (h2f((u16)(aw[i] >> 16))    + h2f((u16)(cw[i] >> 16)))    * il;
        ow[i] = (uint)f2bf(r0) | ((uint)f2bf(r1) << 16);
    }
    uint4 o4; o4.x = ow[0]; o4.y = ow[1]; o4.z = ow[2]; o4.w = ow[3];
    *(uint4*)&attb[gi] = o4;
}

// ---------------------------------------------------------------------------
extern "C" void kernel_launch(void* const* d_in, const int* in_sizes, int n_in,
                              void* d_out, int out_size, void* d_ws, size_t ws_size,
                              hipStream_t stream) {
    const float* x    = (const float*)d_in[0];
    const float* Wqkv = (const float*)d_in[1];
    const float* bqkv = (const float*)d_in[2];
    const float* Wout = (const float*)d_in[3];
    const float* bout = (const float*)d_in[4];
    float* out = (float*)d_out;

    u16*   xb    = (u16*)d_ws;                               //  8 MB [4096][1024]
    u16*   WqT   = xb    + (size_t)4096 * 1024;              //  6 MB [3072][1024]
    u16*   WoT   = WqT   + (size_t)3072 * 1024;              //  2 MB [1024][1024]
    u16*   qkvb  = WoT   + (size_t)1024 * 1024;              // 16 MB [4096][2048] Q,K
    u16*   attb  = qkvb  + (size_t)4096 * 2048;              //  8 MB [4096][1024]
    u16*   vglob = attb  + (size_t)4096 * 1024;              //  8 MB [2][16][64][2048]
    u16*   wsO   = vglob + (size_t)4096 * 2048;              // 16 MB [2][4096][1024] fp16
    float* wsL   = (float*)(wsO + (size_t)2 * 4096 * 1024);  // 512 KB [2][16][4096]

    cvt_bf16<<<dim3((4096 * 1024) / 8 / 256), dim3(256), 0, stream>>>(x, xb);
    transpose_cvt<<<dim3(3072 / 64, 1024 / 64), dim3(256), 0, stream>>>(Wqkv, WqT, 1024, 3072);
    transpose_cvt<<<dim3(1024 / 64, 1024 / 64), dim3(256), 0, stream>>>(Wout, WoT, 1024, 1024);

    gemm_bt<1><<<dim3(3072 / 128, 4096 / 128), dim3(256), 0, stream>>>(
        xb, WqT, bqkv, qkvb, vglob, 4096, 3072, 1024);

    attn_split<<<dim3(Hh * Bb, 32), dim3(256), 0, stream>>>(qkvb, vglob, wsO, wsL);

    combine<<<dim3((4096 * 1024) / 8 / 256), dim3(256), 0, stream>>>(wsO, wsL, attb);

    gemm_bt<0><<<dim3(1024 / 128, 4096 / 128), dim3(256), 0, stream>>>(
        attb, WoT, bout, out, nullptr, 4096, 1024, 1024);
}